// Round 10
// baseline (333.580 us; speedup 1.0000x reference)
//
#include <hip/hip_runtime.h>
#include <math.h>

static constexpr int DC  = 4096;   // D_CAT
static constexpr int NM1 = 4095;   // D_CAT - 1
static constexpr int HID = 256;
static constexpr int BB  = 4096;   // batch
static constexpr double LOG2PI_D = 1.8378770664093454835;

typedef __attribute__((ext_vector_type(8))) __bf16 bf16x8;
typedef __attribute__((ext_vector_type(4))) __bf16 bf16x4;
typedef __attribute__((ext_vector_type(2))) __bf16 bf16x2;
typedef __attribute__((ext_vector_type(4))) float  f32x4;

__device__ __forceinline__ void async16(const __bf16* g, __bf16* l) {
    __builtin_amdgcn_global_load_lds(
        (const __attribute__((address_space(1))) void*)g,
        (__attribute__((address_space(3))) void*)l, 16, 0, 0);
}

// ---- pre: decW transpose [0,1024) + Helmert coeffs [1024,1040) + scalars (1040) ----
__global__ __launch_bounds__(256) void k_pre(
    const float* __restrict__ decW, const float* __restrict__ Psi,
    const float* __restrict__ lv, const float* __restrict__ lss,
    __bf16* __restrict__ decWT, float* __restrict__ av, float* __restrict__ bv,
    float* __restrict__ Dv, float* __restrict__ scal)
{
    __shared__ float tp[32][33];
    const int t = threadIdx.x;
    const int blk = blockIdx.x;
    if (blk < 1024) {
        int bx = blk & 7, by = blk >> 3;
        int tx = t & 31, ty = t >> 5;
        int r0 = by * 32, c0 = bx * 32;
        #pragma unroll
        for (int i = 0; i < 4; i++) {
            int r = r0 + ty + i * 8, c = c0 + tx;
            tp[ty + i * 8][tx] = (r < NM1 && c < HID) ? decW[(size_t)r * HID + c] : 0.f;
        }
        __syncthreads();
        #pragma unroll
        for (int i = 0; i < 4; i++) {
            int c = c0 + ty + i * 8, r = r0 + tx;
            decWT[(size_t)c * DC + r] = (__bf16)tp[tx][ty + i * 8];
        }
    } else if (blk < 1040) {
        int r = (blk - 1024) * 256 + t;
        if (r < NM1) {
            av[r] = Psi[(size_t)r * DC];
            bv[r] = -Psi[(size_t)r * DC + r + 1];
        } else { av[r] = 0.f; bv[r] = 0.f; }
    } else {
        float v = lv[t];
        Dv[t] = expf(v);
        for (int o = 32; o > 0; o >>= 1) v += __shfl_down(v, o);
        __shared__ float red[4];
        if ((t & 63) == 0) red[t >> 6] = v;
        __syncthreads();
        if (t == 0) {
            scal[0] = expf(lss[0]);
            scal[1] = red[0] + red[1] + red[2] + red[3];
        }
    }
}

// ---- wtw: WtW = decWT @ decWT^T, 16 tiles x 16 K-slices = 256 blocks ----
// Split out of the row kernel so its MFMA accumulator registers don't share
// the unified VGPR budget with the (256,8)-bounded row kernel.
__global__ __launch_bounds__(256) void k_wtw(
    const __bf16* __restrict__ decWT, float* __restrict__ WtW)
{
    __shared__ __bf16 As[64 * 32];
    __shared__ __bf16 Bs[64 * 32];
    const int t = threadIdx.x;
    const int lane = t & 63, w = t >> 6;
    const int blk = blockIdx.x;
    const int mn = blk & 15, sl = blk >> 4;
    const int m0 = (mn >> 2) * 64, n0 = (mn & 3) * 64, kb = sl * 256;
    const int ln = lane & 15, q = lane >> 4;
    const int wm = w >> 1, wn = w & 1;
    f32x4 acc[2][2] = {};
    for (int k0 = kb; k0 < kb + 256; k0 += 32) {
        async16(decWT + (size_t)(m0 + (t >> 2)) * DC + k0 + (t & 3) * 8, As + t * 8);
        async16(decWT + (size_t)(n0 + (t >> 2)) * DC + k0 + (t & 3) * 8, Bs + t * 8);
        __syncthreads();
        bf16x8 af[2], bfr[2];
        #pragma unroll
        for (int i = 0; i < 2; i++) {
            af[i]  = *(const bf16x8*)(As + (wm * 32 + i * 16 + ln) * 32 + q * 8);
            bfr[i] = *(const bf16x8*)(Bs + (wn * 32 + i * 16 + ln) * 32 + q * 8);
        }
        #pragma unroll
        for (int mi = 0; mi < 2; mi++)
            #pragma unroll
            for (int ni = 0; ni < 2; ni++)
                acc[mi][ni] = __builtin_amdgcn_mfma_f32_16x16x32_bf16(af[mi], bfr[ni], acc[mi][ni], 0, 0, 0);
        __syncthreads();
    }
    #pragma unroll
    for (int mi = 0; mi < 2; mi++)
        #pragma unroll
        for (int rr = 0; rr < 4; rr++) {
            int m = m0 + wm * 32 + mi * 16 + q * 4 + rr;
            #pragma unroll
            for (int ni = 0; ni < 2; ni++)
                atomicAdd(&WtW[(size_t)m * HID + n0 + wn * 32 + ni * 16 + ln], acc[mi][ni][rr]);
        }
}

// ---- rows: encscan [0,256) + rows [256, 256+BB). NO MFMA in this kernel. ----
// (256,8): all 64 regs/wave go to arch registers. Diet: bvc loaded post-B2,
// eprev/bprev/xnl re-read post-B2, ntot/sumlg kept in LDS until writeout
// (se/sx use red[16..23] so red[0..7] survive). Arithmetic order unchanged.
// Spill tripwire: WRITE_SIZE >> 69 MB.
__global__ __launch_bounds__(256, 8) void k_rows(
    const float* __restrict__ x, const float* __restrict__ eta,
    const float* __restrict__ encW,
    const float* __restrict__ av, const float* __restrict__ bv,
    float* __restrict__ multv, float* __restrict__ eta2,
    __bf16* __restrict__ clrB, __bf16* __restrict__ etaB,
    __bf16* __restrict__ encPsiB)
{
    __shared__ float smemf[2400];
    const int t = threadIdx.x;
    const int blk = blockIdx.x;
    const int lane = t & 63, w = t >> 6;

    if (blk >= 256) {
        __bf16* es    = (__bf16*)smemf;          // [4096] bf16 = 2048 floats
        float* red    = smemf + 2048;            // [24]
        float* wsumE  = smemf + 2072;            // [4]
        float* wsumX  = smemf + 2076;            // [4]
        float* firstX = smemf + 2080;            // [256]
        float* lutL   = smemf + 2336;            // [32]
        float* lutG   = smemf + 2368;            // [32]
        const int b = blk - 256;
        const int j0 = t * 16;

        // P0: x contiguous per-thread loads (row base 16B-aligned)
        const float4* xrow = (const float4*)(x + (size_t)b * DC + j0);
        float4 xq[4];
        #pragma unroll
        for (int i = 0; i < 4; i++) xq[i] = xrow[i];

        // eta strided loads
        const float* erow = eta + (size_t)b * NM1;
        float ee[16];
        #pragma unroll
        for (int i = 0; i < 16; i++) { int j = i * 256 + t; ee[i] = (j < NM1) ? erow[j] : 0.f; }

        if (t < 32) { float f = (float)t + 1.f; lutL[t] = logf(f); lutG[t] = lgammaf(f); }
        __syncthreads();   // B0: LUT visible

        // stats over x; pack x to bf16 (counts 0..19 -> exact)
        bf16x8 xp0, xp1;
        float s = 0.f, slg = 0.f, slp = 0.f;
        {
            float xv[16];
            #pragma unroll
            for (int i = 0; i < 4; i++) {
                xv[i * 4 + 0] = xq[i].x; xv[i * 4 + 1] = xq[i].y;
                xv[i * 4 + 2] = xq[i].z; xv[i * 4 + 3] = xq[i].w;
            }
            #pragma unroll
            for (int i = 0; i < 16; i++) {
                float vf = xv[i];
                int iv = (int)vf;
                float l, g;
                if (vf == (float)iv && iv >= 0 && iv < 32) { l = lutL[iv]; g = lutG[iv]; }
                else { l = logf(vf + 1.f); g = lgammaf(vf + 1.f); }
                s += vf; slg += g; slp += l;
            }
            #pragma unroll
            for (int i = 0; i < 8; i++) { xp0[i] = (__bf16)xv[i]; xp1[i] = (__bf16)xv[i + 8]; }
            firstX[t] = xv[0];
        }
        // e2 + es (bf16) writes from strided eta regs
        float e2 = 0.f;
        #pragma unroll
        for (int i = 0; i < 16; i++) {
            float e = ee[i];
            e2 += e * e;
            es[i * 256 + t] = (__bf16)e;
        }
        for (int o = 32; o > 0; o >>= 1) {
            s += __shfl_down(s, o); slg += __shfl_down(slg, o);
            slp += __shfl_down(slp, o); e2 += __shfl_down(e2, o);
        }
        if (lane == 0) { red[w] = s; red[4 + w] = slg; red[8 + w] = slp; red[12 + w] = e2; }
        __syncthreads();   // B1: red + es + firstX visible

        {
            const float m = (red[8] + red[9] + red[10] + red[11]) * (1.f / DC);
            // clrB: recompute l from packed x (identical LUT/logf expression)
            bf16x8 c0, c1;
            #pragma unroll
            for (int i = 0; i < 16; i++) {
                float vf = (i < 8) ? (float)xp0[i & 7] : (float)xp1[i & 7];
                int iv = (int)vf;
                float l = (vf == (float)iv && iv >= 0 && iv < 32) ? lutL[iv] : logf(vf + 1.f);
                if (i < 8) c0[i & 7] = (__bf16)(l - m); else c1[i & 7] = (__bf16)(l - m);
            }
            *(bf16x8*)(clrB + (size_t)b * DC + j0)     = c0;
            *(bf16x8*)(clrB + (size_t)b * DC + j0 + 8) = c1;
        }

        // eta (bf16, packed) -> etaB store; keep packed for the scan
        bf16x8 e0 = *(const bf16x8*)(es + j0);
        bf16x8 e1 = *(const bf16x8*)(es + j0 + 8);
        *(bf16x8*)(etaB + (size_t)b * DC + j0)     = e0;
        *(bf16x8*)(etaB + (size_t)b * DC + j0 + 8) = e1;

        // avc only (bvc deferred to post-B2)
        float avc[16];
        #pragma unroll
        for (int i = 0; i < 16; i += 4) {
            float4 a4 = *(const float4*)(av + j0 + i);
            avc[i] = a4.x; avc[i + 1] = a4.y; avc[i + 2] = a4.z; avc[i + 3] = a4.w;
        }

        // scan pass 1
        float localE = 0.f, localX = 0.f;
        #pragma unroll
        for (int i = 0; i < 16; i++) {
            float evi = (i < 8) ? (float)e0[i & 7] : (float)e1[i & 7];
            float xvi = (i < 8) ? (float)xp0[i & 7] : (float)xp1[i & 7];
            localE += evi * avc[i]; localX += xvi;
        }
        float incE = localE, incX = localX;
        #pragma unroll
        for (int o = 1; o < 64; o <<= 1) {
            float vE = __shfl_up(incE, o), vX = __shfl_up(incX, o);
            if (lane >= o) { incE += vE; incX += vX; }
        }
        if (lane == 63) { wsumE[w] = incE; wsumX[w] = incX; }
        __syncthreads();   // B2: wsum visible

        float woffE = 0.f, woffX = 0.f;
        for (int i = 0; i < w; i++) { woffE += wsumE[i]; woffX += wsumX[i]; }
        const float U = wsumE[0] + wsumE[1] + wsumE[2] + wsumE[3];
        float runE = woffE + incE - localE;
        float Xrun = woffX + incX - localX;

        // re-read boundary values (es/firstX unchanged since B1; bv from L2)
        float eprev = (t > 0) ? (float)es[j0 - 1] : 0.f;
        float bprev = (t > 0) ? bv[j0 - 1] : 0.f;
        float xnl   = (t < 255) ? firstX[t + 1] : 0.f;
        // bvc loaded late (only used in this pass)
        float bvc[16];
        #pragma unroll
        for (int i = 0; i < 16; i += 4) {
            float4 b4 = *(const float4*)(bv + j0 + i);
            bvc[i] = b4.x; bvc[i + 1] = b4.y; bvc[i + 2] = b4.z; bvc[i + 3] = b4.w;
        }

        float se = 0.f, sx = 0.f;
        float pE = eprev, pB = bprev;   // carry: ev[i-1], bvc[i-1]
        #pragma unroll
        for (int i = 0; i < 16; i++) {
            float evi = (i < 8) ? (float)e0[i & 7] : (float)e1[i & 7];
            float xvi = (i < 8) ? (float)xp0[i & 7] : (float)xp1[i & 7];
            float Tj = U - runE;
            runE += evi * avc[i];
            float pw = pE * pB;
            float l = Tj - pw;
            se += expf(l);
            Xrun += xvi;
            float xn = (i < 15) ? ((i + 1 < 8) ? (float)xp0[(i + 1) & 7] : (float)xp1[(i + 1) & 7]) : xnl;
            sx += evi * (avc[i] * Xrun - bvc[i] * xn);
            pE = evi; pB = bvc[i];
        }
        for (int o = 32; o > 0; o >>= 1) {
            se += __shfl_down(se, o); sx += __shfl_down(sx, o);
        }
        if (lane == 0) { red[16 + w] = se; red[20 + w] = sx; }
        __syncthreads();   // B3
        if (t == 0) {
            float ntotv  = red[0] + red[1] + red[2] + red[3];
            float sumlgv = red[4] + red[5] + red[6] + red[7];
            float S1t = red[16] + red[17] + red[18] + red[19];
            float S2t = red[20] + red[21] + red[22] + red[23];
            float e2t = red[12] + red[13] + red[14] + red[15];
            double mult = (double)lgammaf(ntotv + 1.f) - (double)sumlgv
                        + (double)S2t - (double)ntotv * (double)logf(S1t);
            multv[b] = (float)mult;
            eta2[b]  = e2t;
        }
    } else {
        // ---------------- encscan (same diet: bvc post-sync) ----------------
        __bf16* es   = (__bf16*)smemf;
        float* wsumE = smemf + 2048;
        const int h = blk;
        const float* erow = encW + (size_t)h * NM1;
        {
            float ee[16];
            #pragma unroll
            for (int i = 0; i < 16; i++) { int j = i * 256 + t; ee[i] = (j < NM1) ? erow[j] : 0.f; }
            #pragma unroll
            for (int i = 0; i < 16; i++) es[i * 256 + t] = (__bf16)ee[i];
        }
        const int j0 = t * 16;
        float avc[16];
        #pragma unroll
        for (int i = 0; i < 16; i += 4) {
            float4 a4 = *(const float4*)(av + j0 + i);
            avc[i] = a4.x; avc[i + 1] = a4.y; avc[i + 2] = a4.z; avc[i + 3] = a4.w;
        }
        __syncthreads();
        bf16x8 e0 = *(const bf16x8*)(es + j0);
        bf16x8 e1 = *(const bf16x8*)(es + j0 + 8);
        float localE = 0.f;
        #pragma unroll
        for (int i = 0; i < 16; i++) {
            float evi = (i < 8) ? (float)e0[i & 7] : (float)e1[i & 7];
            localE += evi * avc[i];
        }
        float incE = localE;
        #pragma unroll
        for (int o = 1; o < 64; o <<= 1) { float vE = __shfl_up(incE, o); if (lane >= o) incE += vE; }
        if (lane == 63) wsumE[w] = incE;
        __syncthreads();
        float woffE = 0.f;
        for (int i = 0; i < w; i++) woffE += wsumE[i];
        const float U = wsumE[0] + wsumE[1] + wsumE[2] + wsumE[3];
        float runE = woffE + incE - localE;
        float eprev = (t > 0) ? (float)es[j0 - 1] : 0.f;
        float bprev = (t > 0) ? bv[j0 - 1] : 0.f;
        float bvc[16];
        #pragma unroll
        for (int i = 0; i < 16; i += 4) {
            float4 b4 = *(const float4*)(bv + j0 + i);
            bvc[i] = b4.x; bvc[i + 1] = b4.y; bvc[i + 2] = b4.z; bvc[i + 3] = b4.w;
        }
        bf16x8 o0, o1;
        float pE = eprev, pB = bprev;
        #pragma unroll
        for (int i = 0; i < 16; i++) {
            float evi = (i < 8) ? (float)e0[i & 7] : (float)e1[i & 7];
            float Tj = U - runE;
            runE += evi * avc[i];
            float pw = pE * pB;
            float l = Tj - pw;
            if (i < 8) o0[i & 7] = (__bf16)l; else o1[i & 7] = (__bf16)l;
            pE = evi; pB = bvc[i];
        }
        *(bf16x8*)(encPsiB + (size_t)h * DC + j0)     = o0;
        *(bf16x8*)(encPsiB + (size_t)h * DC + j0 + 8) = o1;
    }
}

// ---- combo2: cap [0,16) first + z_mean/etaW GEMMs [16,528) (BK=64, split-K 4) ----
// GEMM: XOR-chunk-swizzled LDS (rule #21). Epilogue writes per-slice PARTIALS
// with plain stores (no device-scope atomics); mfma_quad sums the 4 slices.
__global__ __launch_bounds__(256) void k_combo2(
    const __bf16* __restrict__ clrB, const __bf16* __restrict__ etaB,
    const __bf16* __restrict__ encPsiB, const __bf16* __restrict__ decWT,
    float* __restrict__ part,
    const float* __restrict__ WtW, const float* __restrict__ Dv,
    const float* __restrict__ scal, __bf16* __restrict__ WtWB,
    __bf16* __restrict__ MinvB, float* __restrict__ scal_out)
{
    __shared__ __bf16 As[64 * 64];    // 8 KB
    __shared__ __bf16 Bs[256 * 64];   // 32 KB
    const int tid = threadIdx.x;
    const int w = tid >> 6, lane = tid & 63;
    const int ln = lane & 15, q = lane >> 4;
    const int wm = w >> 1, wn = w & 1;
    const int bid = blockIdx.x;

    if (bid >= 16) {
        const int idx = bid - 16;
        const int g = idx >> 8, r = idx & 255, sl = r >> 6, mt = r & 63;
        const __bf16* A  = g ? etaB  : clrB;
        const __bf16* Bt = g ? decWT : encPsiB;
        float* C = part + ((size_t)(g * 4 + sl) << 20);   // this block's partial slice
        const int m0 = mt * 64, kb = sl * 1024;
        f32x4 acc[2][8] = {};
        for (int k0 = kb; k0 < kb + 1024; k0 += 64) {
            #pragma unroll
            for (int j = 0; j < 2; j++) {
                int c = j * 256 + tid;
                int row = c >> 3, ch = c & 7;
                async16(A + (size_t)(m0 + row) * DC + k0 + (ch ^ (row & 7)) * 8, As + c * 8);
            }
            #pragma unroll
            for (int j = 0; j < 8; j++) {
                int c = j * 256 + tid;
                int row = c >> 3, ch = c & 7;
                async16(Bt + (size_t)row * DC + k0 + (ch ^ (row & 7)) * 8, Bs + c * 8);
            }
            __syncthreads();
            #pragma unroll
            for (int jj = 0; jj < 2; jj++) {
                bf16x8 af[2], bfr[8];
                #pragma unroll
                for (int i = 0; i < 2; i++) {
                    int arow = wm * 32 + i * 16 + ln;
                    af[i]  = *(const bf16x8*)(As + arow * 64 + ((jj * 4 + q) ^ (arow & 7)) * 8);
                }
                #pragma unroll
                for (int i = 0; i < 8; i++) {
                    int brow = wn * 128 + i * 16 + ln;
                    bfr[i] = *(const bf16x8*)(Bs + brow * 64 + ((jj * 4 + q) ^ (brow & 7)) * 8);
                }
                #pragma unroll
                for (int mi = 0; mi < 2; mi++)
                    #pragma unroll
                    for (int ni = 0; ni < 8; ni++)
                        acc[mi][ni] = __builtin_amdgcn_mfma_f32_16x16x32_bf16(af[mi], bfr[ni], acc[mi][ni], 0, 0, 0);
            }
            __syncthreads();
        }
        #pragma unroll
        for (int mi = 0; mi < 2; mi++)
            #pragma unroll
            for (int rr = 0; rr < 4; rr++) {
                int m = m0 + wm * 32 + mi * 16 + q * 4 + rr;
                #pragma unroll
                for (int ni = 0; ni < 8; ni++) {
                    int n = wn * 128 + ni * 16 + ln;
                    C[(size_t)m * HID + n] = acc[mi][ni][rr];
                }
            }
    } else {
        // ---- cap: B2 = B@B (64x64 tile); Minv = (I - B + B2)*diag(Dv); traces ----
        __shared__ float dvs[HID];
        __shared__ float redc[8];
        const int w2 = bid;
        const int m0 = (w2 >> 2) * 64, n0 = (w2 & 3) * 64;
        dvs[tid] = Dv[tid];
        __syncthreads();
        const float rv = 1.f / scal[0];
        f32x4 acc[2][2] = {};
        for (int k0 = 0; k0 < HID; k0 += 32) {
            {
                int row = tid >> 2, kc = tid & 3;
                const float* srcA = WtW + (size_t)(m0 + row) * HID + k0 + kc * 8;
                const float* srcB = WtW + (size_t)(n0 + row) * HID + k0 + kc * 8;
                float sA = dvs[m0 + row] * rv;
                bf16x8 a8, b8;
                #pragma unroll
                for (int u = 0; u < 8; u++) {
                    a8[u] = (__bf16)(srcA[u] * sA);
                    b8[u] = (__bf16)(srcB[u] * dvs[k0 + kc * 8 + u] * rv);
                }
                *(bf16x8*)(As + tid * 8) = a8;
                *(bf16x8*)(Bs + tid * 8) = b8;
            }
            __syncthreads();
            bf16x8 af[2], bfr[2];
            #pragma unroll
            for (int i = 0; i < 2; i++) {
                af[i]  = *(const bf16x8*)(As + (wm * 32 + i * 16 + ln) * 32 + q * 8);
                bfr[i] = *(const bf16x8*)(Bs + (wn * 32 + i * 16 + ln) * 32 + q * 8);
            }
            #pragma unroll
            for (int mi = 0; mi < 2; mi++)
                #pragma unroll
                for (int ni = 0; ni < 2; ni++)
                    acc[mi][ni] = __builtin_amdgcn_mfma_f32_16x16x32_bf16(af[mi], bfr[ni], acc[mi][ni], 0, 0, 0);
            __syncthreads();
        }
        float t1p = 0.f, t2p = 0.f;
        #pragma unroll
        for (int mi = 0; mi < 2; mi++)
            #pragma unroll
            for (int rr = 0; rr < 4; rr++) {
                int m = m0 + wm * 32 + mi * 16 + q * 4 + rr;
                #pragma unroll
                for (int ni = 0; ni < 2; ni++) {
                    int n = n0 + wn * 32 + ni * 16 + ln;
                    float wmn = WtW[(size_t)m * HID + n];
                    float Bmn = dvs[m] * wmn * rv;
                    float Bnm = dvs[n] * wmn * rv;
                    float mv = (((m == n) ? 1.f : 0.f) - Bmn + acc[mi][ni][rr]) * dvs[n];
                    MinvB[(size_t)m * HID + n] = (__bf16)mv;
                    WtWB[(size_t)m * HID + n] = (__bf16)wmn;
                    t2p += Bmn * Bnm;
                    if (m == n) t1p += Bmn;
                }
            }
        for (int o = 32; o > 0; o >>= 1) { t1p += __shfl_down(t1p, o); t2p += __shfl_down(t2p, o); }
        if (lane == 0) { redc[w] = t1p; redc[4 + w] = t2p; }
        __syncthreads();
        if (tid == 0) {
            atomicAdd(&scal_out[2], redc[0] + redc[1] + redc[2] + redc[3]);
            atomicAdd(&scal_out[3], redc[4] + redc[5] + redc[6] + redc[7]);
        }
    }
}

// ---- fused quad: Zw = z@WtW, dW in LDS, T = dW@Minv, row dots; 16-row tiles ----
// z_mean/etaW are read as the sum of 4 split-K partial slices (part[0..3]=z,
// part[4..7]=etaW). 64B-stride tiles swizzled with chunk ^= (row>>1)&3.
__global__ __launch_bounds__(256) void mfma_quad(
    const float* __restrict__ part,
    const __bf16* __restrict__ WtWB, const __bf16* __restrict__ MinvB,
    float* __restrict__ r0a, float* __restrict__ r1a, float* __restrict__ r2a,
    float* __restrict__ r3a)
{
    __shared__ __bf16 As[16 * 32];
    __shared__ __bf16 Bs[256 * 32];
    __shared__ __bf16 dWs[16 * 264];
    const int tid = threadIdx.x;
    const int w = tid >> 6, lane = tid & 63;
    const int ln = lane & 15, q = lane >> 4;
    const int m0 = blockIdx.x * 16;
    const float* zp = part;
    const float* ep = part + ((size_t)4 << 20);
    const size_t SL = (size_t)1 << 20;

    f32x4 acc[4] = {};
    for (int k0 = 0; k0 < HID; k0 += 32) {
        {
            int row = tid >> 4, kc = tid & 15;
            size_t off = (size_t)(m0 + row) * HID + k0 + kc * 2;
            float2 v0 = *(const float2*)(zp + off);
            float2 v1 = *(const float2*)(zp + SL + off);
            float2 v2 = *(const float2*)(zp + 2 * SL + off);
            float2 v3 = *(const float2*)(zp + 3 * SL + off);
            float vx = v0.x + v1.x + v2.x + v3.x;
            float vy = v0.y + v1.y + v2.y + v3.y;
            bf16x2 b2 = {(__bf16)vx, (__bf16)vy};
            int ch = kc >> 2, wi = kc & 3;
            *(bf16x2*)(As + row * 32 + ((ch ^ ((row >> 1) & 3)) * 8) + wi * 2) = b2;
        }
        #pragma unroll
        for (int j = 0; j < 4; j++) {
            int c = j * 256 + tid;
            int row = c >> 2, ch = c & 3;
            async16(WtWB + (size_t)row * HID + k0 + (ch ^ ((row >> 1) & 3)) * 8, Bs + c * 8);
        }
        __syncthreads();
        bf16x8 af = *(const bf16x8*)(As + ln * 32 + ((q ^ ((ln >> 1) & 3)) * 8));
        #pragma unroll
        for (int ni = 0; ni < 4; ni++) {
            int brow = w * 64 + ni * 16 + ln;
            bf16x8 bfr = *(const bf16x8*)(Bs + brow * 32 + ((q ^ ((ln >> 1) & 3)) * 8));
            acc[ni] = __builtin_amdgcn_mfma_f32_16x16x32_bf16(af, bfr, acc[ni], 0, 0, 0);
        }
        __syncthreads();
    }
    #pragma unroll
    for (int rr = 0; rr < 4; rr++) {
        int lm = q * 4 + rr;
        int m = m0 + lm;
        float s0 = 0.f, s1 = 0.f, s3 = 0.f;
        #pragma unroll
        for (int ni = 0; ni < 4; ni++) {
            int n = w * 64 + ni * 16 + ln;
            size_t o2 = (size_t)m * HID + n;
            float zv = zp[o2] + zp[SL + o2] + zp[2 * SL + o2] + zp[3 * SL + o2];
            float ew = ep[o2] + ep[SL + o2] + ep[2 * SL + o2] + ep[3 * SL + o2];
            float dv = ew - acc[ni][rr];
            dWs[lm * 264 + n] = (__bf16)dv;
            s0 += ew * zv; s1 += dv * zv; s3 += zv * zv;
        }
        #pragma unroll
        for (int o = 1; o < 16; o <<= 1) {
            s0 += __shfl_xor(s0, o); s1 += __shfl_xor(s1, o); s3 += __shfl_xor(s3, o);
        }
        if (ln == 0) {
            atomicAdd(&r0a[m], s0); atomicAdd(&r1a[m], s1); atomicAdd(&r3a[m], s3);
        }
    }

    f32x4 acc2[4] = {};
    for (int k0 = 0; k0 < HID; k0 += 32) {
        #pragma unroll
        for (int j = 0; j < 4; j++) {
            int c = j * 256 + tid;
            int row = c >> 2, ch = c & 3;
            async16(MinvB + (size_t)row * HID + k0 + (ch ^ ((row >> 1) & 3)) * 8, Bs + c * 8);
        }
        __syncthreads();
        bf16x8 af = *(const bf16x8*)(dWs + ln * 264 + k0 + q * 8);
        #pragma unroll
        for (int ni = 0; ni < 4; ni++) {
            int brow = w * 64 + ni * 16 + ln;
            bf16x8 bfr = *(const bf16x8*)(Bs + brow * 32 + ((q ^ ((ln >> 1) & 3)) * 8));
            acc2[ni] = __builtin_amdgcn_mfma_f32_16x16x32_bf16(af, bfr, acc2[ni], 0, 0, 0);
        }
        __syncthreads();
    }
    #pragma unroll
    for (int rr = 0; rr < 4; rr++) {
        int lm = q * 4 + rr;
        int m = m0 + lm;
        float s2 = 0.f;
        #pragma unroll
        for (int ni = 0; ni < 4; ni++) {
            int n = w * 64 + ni * 16 + ln;
            s2 += (float)dWs[lm * 264 + n] * acc2[ni][rr];
        }
        #pragma unroll
        for (int o = 1; o < 16; o <<= 1) s2 += __shfl_xor(s2, o);
        if (ln == 0) atomicAdd(&r2a[m], s2);
    }
}

// ---- final assembly ----
__global__ void k_final(const float* __restrict__ multv, const float* __restrict__ eta2,
                        const float* __restrict__ r0a, const float* __restrict__ r1a,
                        const float* __restrict__ r2a, const float* __restrict__ r3a,
                        const float* __restrict__ scal, const float* __restrict__ lss,
                        float* __restrict__ out) {
    int t = threadIdx.x;
    float var = scal[0];
    float rv = 1.f / var;
    double am = 0.0, aq = 0.0, az = 0.0;
    for (int b = t; b < BB; b += 256) {
        am += (double)multv[b];
        aq += (double)((eta2[b] - r0a[b] - r1a[b]) * rv - r2a[b] * rv * rv);
        az += (double)r3a[b];
    }
    for (int o = 32; o > 0; o >>= 1) {
        am += __shfl_down(am, o); aq += __shfl_down(aq, o); az += __shfl_down(az, o);
    }
    __shared__ double red[3][4];
    if ((t & 63) == 0) { int w = t >> 6; red[0][w] = am; red[1][w] = aq; red[2][w] = az; }
    __syncthreads();
    if (t == 0) {
        double mm = (red[0][0] + red[0][1] + red[0][2] + red[0][3]) / (double)BB;
        double mq = (red[1][0] + red[1][1] + red[1][2] + red[1][3]) / (double)BB;
        double mz = (red[2][0] + red[2][1] + red[2][2] + red[2][3]) / ((double)BB * (double)HID);
        double t1 = scal[2], t2 = scal[3];
        double logdetIB = t1 - t2 * 0.5;
        double sumlv = (double)scal[1];
        double logdetM = -sumlv + logdetIB;
        double logdet_sigma = (double)NM1 * (double)lss[0] + sumlv + logdetM;
        double logit_loss = -0.5 * ((double)NM1 * LOG2PI_D + logdet_sigma + mq);
        double prior_loss = -0.5 * mz - 0.5 * LOG2PI_D;
        out[0] = (float)(-(mm + logit_loss + prior_loss));
    }
}

// ---------------- launcher ----------------

extern "C" void kernel_launch(void* const* d_in, const int* in_sizes, int n_in,
                              void* d_out, int out_size, void* d_ws, size_t ws_size,
                              hipStream_t stream) {
    (void)in_sizes; (void)n_in; (void)out_size; (void)ws_size;
    const float* x    = (const float*)d_in[0];
    const float* Psi  = (const float*)d_in[1];
    const float* encW = (const float*)d_in[2];
    const float* decW = (const float*)d_in[3];
    const float* lv   = (const float*)d_in[4];
    const float* lss  = (const float*)d_in[5];
    const float* eta  = (const float*)d_in[6];
    float* out = (float*)d_out;

    float* wp = (float*)d_ws;
    // --- split-K partials: z slices [0,4), etaW slices [4,8), 1M floats each ---
    float* part   = wp;                      // 8M floats = 32 MB (fully overwritten)
    // --- contiguous memset region (atomic targets) ---
    float* WtW    = part + ((size_t)8 << 20); // 64K
    float* r0a    = WtW    + 65536;          // 4K each
    float* r1a    = r0a    + 4096;
    float* r2a    = r1a    + 4096;
    float* r3a    = r2a    + 4096;
    float* scal   = r3a    + 4096;           // 16
    // --- rest ---
    float* av     = scal   + 16;
    float* bv     = av     + 4096;
    float* multv  = bv     + 4096;
    float* eta2   = multv  + 4096;
    float* Dv     = eta2   + 4096;           // 256
    __bf16* clrB    = (__bf16*)(Dv + 256);
    __bf16* etaB    = clrB    + (1 << 24);
    __bf16* encPsiB = etaB    + (1 << 24);   // 1M
    __bf16* decWT   = encPsiB + (1 << 20);   // 1M
    __bf16* WtWB    = decWT   + (1 << 20);   // 64K each
    __bf16* MinvB   = WtWB    + 65536;

    hipMemsetAsync(WtW, 0, (size_t)(65536 + 4 * 4096 + 16) * sizeof(float), stream);

    k_pre<<<1041, 256, 0, stream>>>(decW, Psi, lv, lss, decWT, av, bv, Dv, scal);

    k_wtw<<<256, 256, 0, stream>>>(decWT, WtW);

    k_rows<<<256 + BB, 256, 0, stream>>>(x, eta, encW, av, bv,
                                         multv, eta2, clrB, etaB, encPsiB);

    k_combo2<<<528, 256, 0, stream>>>(clrB, etaB, encPsiB, decWT, part,
                                      WtW, Dv, scal, WtWB, MinvB, scal);

    mfma_quad<<<256, 256, 0, stream>>>(part, WtWB, MinvB, r0a, r1a, r2a, r3a);

    k_final<<<1, 256, 0, stream>>>(multv, eta2, r0a, r1a, r2a, r3a, scal, lss, out);
}

// Round 11
// 291.951 us; speedup vs baseline: 1.1426x; 1.1426x over previous
//
#include <hip/hip_runtime.h>
#include <math.h>

static constexpr int DC  = 4096;   // D_CAT
static constexpr int NM1 = 4095;   // D_CAT - 1
static constexpr int HID = 256;
static constexpr int BB  = 4096;   // batch
static constexpr double LOG2PI_D = 1.8378770664093454835;

typedef __attribute__((ext_vector_type(8))) __bf16 bf16x8;
typedef __attribute__((ext_vector_type(4))) __bf16 bf16x4;
typedef __attribute__((ext_vector_type(2))) __bf16 bf16x2;
typedef __attribute__((ext_vector_type(4))) float  f32x4;

__device__ __forceinline__ void async16(const __bf16* g, __bf16* l) {
    __builtin_amdgcn_global_load_lds(
        (const __attribute__((address_space(1))) void*)g,
        (__attribute__((address_space(3))) void*)l, 16, 0, 0);
}

// ---- pre: decW transpose [0,1024) + Helmert coeffs [1024,1040) + scalars (1040) ----
__global__ __launch_bounds__(256) void k_pre(
    const float* __restrict__ decW, const float* __restrict__ Psi,
    const float* __restrict__ lv, const float* __restrict__ lss,
    __bf16* __restrict__ decWT, float* __restrict__ av, float* __restrict__ bv,
    float* __restrict__ Dv, float* __restrict__ scal)
{
    __shared__ float tp[32][33];
    const int t = threadIdx.x;
    const int blk = blockIdx.x;
    if (blk < 1024) {
        int bx = blk & 7, by = blk >> 3;
        int tx = t & 31, ty = t >> 5;
        int r0 = by * 32, c0 = bx * 32;
        #pragma unroll
        for (int i = 0; i < 4; i++) {
            int r = r0 + ty + i * 8, c = c0 + tx;
            tp[ty + i * 8][tx] = (r < NM1 && c < HID) ? decW[(size_t)r * HID + c] : 0.f;
        }
        __syncthreads();
        #pragma unroll
        for (int i = 0; i < 4; i++) {
            int c = c0 + ty + i * 8, r = r0 + tx;
            decWT[(size_t)c * DC + r] = (__bf16)tp[tx][ty + i * 8];
        }
    } else if (blk < 1040) {
        int r = (blk - 1024) * 256 + t;
        if (r < NM1) {
            av[r] = Psi[(size_t)r * DC];
            bv[r] = -Psi[(size_t)r * DC + r + 1];
        } else { av[r] = 0.f; bv[r] = 0.f; }
    } else {
        float v = lv[t];
        Dv[t] = expf(v);
        for (int o = 32; o > 0; o >>= 1) v += __shfl_down(v, o);
        __shared__ float red[4];
        if ((t & 63) == 0) red[t >> 6] = v;
        __syncthreads();
        if (t == 0) {
            scal[0] = expf(lss[0]);
            scal[1] = red[0] + red[1] + red[2] + red[3];
        }
    }
}

// ---- wtw: WtW = decWT @ decWT^T, 16 tiles x 16 K-slices = 256 blocks ----
// Separate kernel so its MFMA accumulators don't inflate k_rows' allocation.
__global__ __launch_bounds__(256) void k_wtw(
    const __bf16* __restrict__ decWT, float* __restrict__ WtW)
{
    __shared__ __bf16 As[64 * 32];
    __shared__ __bf16 Bs[64 * 32];
    const int t = threadIdx.x;
    const int lane = t & 63, w = t >> 6;
    const int blk = blockIdx.x;
    const int mn = blk & 15, sl = blk >> 4;
    const int m0 = (mn >> 2) * 64, n0 = (mn & 3) * 64, kb = sl * 256;
    const int ln = lane & 15, q = lane >> 4;
    const int wm = w >> 1, wn = w & 1;
    f32x4 acc[2][2] = {};
    for (int k0 = kb; k0 < kb + 256; k0 += 32) {
        async16(decWT + (size_t)(m0 + (t >> 2)) * DC + k0 + (t & 3) * 8, As + t * 8);
        async16(decWT + (size_t)(n0 + (t >> 2)) * DC + k0 + (t & 3) * 8, Bs + t * 8);
        __syncthreads();
        bf16x8 af[2], bfr[2];
        #pragma unroll
        for (int i = 0; i < 2; i++) {
            af[i]  = *(const bf16x8*)(As + (wm * 32 + i * 16 + ln) * 32 + q * 8);
            bfr[i] = *(const bf16x8*)(Bs + (wn * 32 + i * 16 + ln) * 32 + q * 8);
        }
        #pragma unroll
        for (int mi = 0; mi < 2; mi++)
            #pragma unroll
            for (int ni = 0; ni < 2; ni++)
                acc[mi][ni] = __builtin_amdgcn_mfma_f32_16x16x32_bf16(af[mi], bfr[ni], acc[mi][ni], 0, 0, 0);
        __syncthreads();
    }
    #pragma unroll
    for (int mi = 0; mi < 2; mi++)
        #pragma unroll
        for (int rr = 0; rr < 4; rr++) {
            int m = m0 + wm * 32 + mi * 16 + q * 4 + rr;
            #pragma unroll
            for (int ni = 0; ni < 2; ni++)
                atomicAdd(&WtW[(size_t)m * HID + n0 + wn * 32 + ni * 16 + ln], acc[mi][ni][rr]);
        }
}

// ---- rows: encscan [0,256) + rows [256, 256+BB). NO MFMA, NO min-waves bound.
// Dieted (packed bf16 x/eta, late bvc, recomputed log) so the allocator can
// naturally land <=64 VGPR (8-wave cliff). Forcing via __launch_bounds__ min-
// waves >4 makes the allocator spill wholesale (rounds 7-10: VGPR 32-40,
// WRITE 138-270 MB) — so no bound here; let it fall where it fits.
__global__ __launch_bounds__(256) void k_rows(
    const float* __restrict__ x, const float* __restrict__ eta,
    const float* __restrict__ encW,
    const float* __restrict__ av, const float* __restrict__ bv,
    float* __restrict__ multv, float* __restrict__ eta2,
    __bf16* __restrict__ clrB, __bf16* __restrict__ etaB,
    __bf16* __restrict__ encPsiB)
{
    __shared__ float smemf[2400];
    const int t = threadIdx.x;
    const int blk = blockIdx.x;
    const int lane = t & 63, w = t >> 6;

    if (blk >= 256) {
        __bf16* es    = (__bf16*)smemf;          // [4096] bf16 = 2048 floats
        float* red    = smemf + 2048;            // [24]
        float* wsumE  = smemf + 2072;            // [4]
        float* wsumX  = smemf + 2076;            // [4]
        float* firstX = smemf + 2080;            // [256]
        float* lutL   = smemf + 2336;            // [32]
        float* lutG   = smemf + 2368;            // [32]
        const int b = blk - 256;
        const int j0 = t * 16;

        // P0: x contiguous per-thread loads (row base 16B-aligned)
        const float4* xrow = (const float4*)(x + (size_t)b * DC + j0);
        float4 xq[4];
        #pragma unroll
        for (int i = 0; i < 4; i++) xq[i] = xrow[i];

        // eta strided loads
        const float* erow = eta + (size_t)b * NM1;
        float ee[16];
        #pragma unroll
        for (int i = 0; i < 16; i++) { int j = i * 256 + t; ee[i] = (j < NM1) ? erow[j] : 0.f; }

        if (t < 32) { float f = (float)t + 1.f; lutL[t] = logf(f); lutG[t] = lgammaf(f); }
        __syncthreads();   // B0: LUT visible

        // stats over x; pack x to bf16 (counts 0..19 -> exact)
        bf16x8 xp0, xp1;
        float s = 0.f, slg = 0.f, slp = 0.f;
        {
            float xv[16];
            #pragma unroll
            for (int i = 0; i < 4; i++) {
                xv[i * 4 + 0] = xq[i].x; xv[i * 4 + 1] = xq[i].y;
                xv[i * 4 + 2] = xq[i].z; xv[i * 4 + 3] = xq[i].w;
            }
            #pragma unroll
            for (int i = 0; i < 16; i++) {
                float vf = xv[i];
                int iv = (int)vf;
                float l, g;
                if (vf == (float)iv && iv >= 0 && iv < 32) { l = lutL[iv]; g = lutG[iv]; }
                else { l = logf(vf + 1.f); g = lgammaf(vf + 1.f); }
                s += vf; slg += g; slp += l;
            }
            #pragma unroll
            for (int i = 0; i < 8; i++) { xp0[i] = (__bf16)xv[i]; xp1[i] = (__bf16)xv[i + 8]; }
            firstX[t] = xv[0];
        }
        // e2 + es (bf16) writes from strided eta regs
        float e2 = 0.f;
        #pragma unroll
        for (int i = 0; i < 16; i++) {
            float e = ee[i];
            e2 += e * e;
            es[i * 256 + t] = (__bf16)e;
        }
        for (int o = 32; o > 0; o >>= 1) {
            s += __shfl_down(s, o); slg += __shfl_down(slg, o);
            slp += __shfl_down(slp, o); e2 += __shfl_down(e2, o);
        }
        if (lane == 0) { red[w] = s; red[4 + w] = slg; red[8 + w] = slp; red[12 + w] = e2; }
        __syncthreads();   // B1: red + es + firstX visible

        {
            const float m = (red[8] + red[9] + red[10] + red[11]) * (1.f / DC);
            // clrB: recompute l from packed x (identical LUT/logf expression)
            bf16x8 c0, c1;
            #pragma unroll
            for (int i = 0; i < 16; i++) {
                float vf = (i < 8) ? (float)xp0[i & 7] : (float)xp1[i & 7];
                int iv = (int)vf;
                float l = (vf == (float)iv && iv >= 0 && iv < 32) ? lutL[iv] : logf(vf + 1.f);
                if (i < 8) c0[i & 7] = (__bf16)(l - m); else c1[i & 7] = (__bf16)(l - m);
            }
            *(bf16x8*)(clrB + (size_t)b * DC + j0)     = c0;
            *(bf16x8*)(clrB + (size_t)b * DC + j0 + 8) = c1;
        }

        // eta (bf16, packed) -> etaB store; keep packed for the scan
        bf16x8 e0 = *(const bf16x8*)(es + j0);
        bf16x8 e1 = *(const bf16x8*)(es + j0 + 8);
        *(bf16x8*)(etaB + (size_t)b * DC + j0)     = e0;
        *(bf16x8*)(etaB + (size_t)b * DC + j0 + 8) = e1;

        // avc only (bvc deferred to post-B2)
        float avc[16];
        #pragma unroll
        for (int i = 0; i < 16; i += 4) {
            float4 a4 = *(const float4*)(av + j0 + i);
            avc[i] = a4.x; avc[i + 1] = a4.y; avc[i + 2] = a4.z; avc[i + 3] = a4.w;
        }

        // scan pass 1
        float localE = 0.f, localX = 0.f;
        #pragma unroll
        for (int i = 0; i < 16; i++) {
            float evi = (i < 8) ? (float)e0[i & 7] : (float)e1[i & 7];
            float xvi = (i < 8) ? (float)xp0[i & 7] : (float)xp1[i & 7];
            localE += evi * avc[i]; localX += xvi;
        }
        float incE = localE, incX = localX;
        #pragma unroll
        for (int o = 1; o < 64; o <<= 1) {
            float vE = __shfl_up(incE, o), vX = __shfl_up(incX, o);
            if (lane >= o) { incE += vE; incX += vX; }
        }
        if (lane == 63) { wsumE[w] = incE; wsumX[w] = incX; }
        __syncthreads();   // B2: wsum visible

        float woffE = 0.f, woffX = 0.f;
        for (int i = 0; i < w; i++) { woffE += wsumE[i]; woffX += wsumX[i]; }
        const float U = wsumE[0] + wsumE[1] + wsumE[2] + wsumE[3];
        float runE = woffE + incE - localE;
        float Xrun = woffX + incX - localX;

        // re-read boundary values (es/firstX unchanged since B1; bv from L2)
        float eprev = (t > 0) ? (float)es[j0 - 1] : 0.f;
        float bprev = (t > 0) ? bv[j0 - 1] : 0.f;
        float xnl   = (t < 255) ? firstX[t + 1] : 0.f;
        // bvc loaded late (only used in this pass)
        float bvc[16];
        #pragma unroll
        for (int i = 0; i < 16; i += 4) {
            float4 b4 = *(const float4*)(bv + j0 + i);
            bvc[i] = b4.x; bvc[i + 1] = b4.y; bvc[i + 2] = b4.z; bvc[i + 3] = b4.w;
        }

        float se = 0.f, sx = 0.f;
        float pE = eprev, pB = bprev;   // carry: ev[i-1], bvc[i-1]
        #pragma unroll
        for (int i = 0; i < 16; i++) {
            float evi = (i < 8) ? (float)e0[i & 7] : (float)e1[i & 7];
            float xvi = (i < 8) ? (float)xp0[i & 7] : (float)xp1[i & 7];
            float Tj = U - runE;
            runE += evi * avc[i];
            float pw = pE * pB;
            float l = Tj - pw;
            se += expf(l);
            Xrun += xvi;
            float xn = (i < 15) ? ((i + 1 < 8) ? (float)xp0[(i + 1) & 7] : (float)xp1[(i + 1) & 7]) : xnl;
            sx += evi * (avc[i] * Xrun - bvc[i] * xn);
            pE = evi; pB = bvc[i];
        }
        for (int o = 32; o > 0; o >>= 1) {
            se += __shfl_down(se, o); sx += __shfl_down(sx, o);
        }
        if (lane == 0) { red[16 + w] = se; red[20 + w] = sx; }
        __syncthreads();   // B3
        if (t == 0) {
            float ntotv  = red[0] + red[1] + red[2] + red[3];
            float sumlgv = red[4] + red[5] + red[6] + red[7];
            float S1t = red[16] + red[17] + red[18] + red[19];
            float S2t = red[20] + red[21] + red[22] + red[23];
            float e2t = red[12] + red[13] + red[14] + red[15];
            double mult = (double)lgammaf(ntotv + 1.f) - (double)sumlgv
                        + (double)S2t - (double)ntotv * (double)logf(S1t);
            multv[b] = (float)mult;
            eta2[b]  = e2t;
        }
    } else {
        // ---------------- encscan (same diet: bvc post-sync) ----------------
        __bf16* es   = (__bf16*)smemf;
        float* wsumE = smemf + 2048;
        const int h = blk;
        const float* erow = encW + (size_t)h * NM1;
        {
            float ee[16];
            #pragma unroll
            for (int i = 0; i < 16; i++) { int j = i * 256 + t; ee[i] = (j < NM1) ? erow[j] : 0.f; }
            #pragma unroll
            for (int i = 0; i < 16; i++) es[i * 256 + t] = (__bf16)ee[i];
        }
        const int j0 = t * 16;
        float avc[16];
        #pragma unroll
        for (int i = 0; i < 16; i += 4) {
            float4 a4 = *(const float4*)(av + j0 + i);
            avc[i] = a4.x; avc[i + 1] = a4.y; avc[i + 2] = a4.z; avc[i + 3] = a4.w;
        }
        __syncthreads();
        bf16x8 e0 = *(const bf16x8*)(es + j0);
        bf16x8 e1 = *(const bf16x8*)(es + j0 + 8);
        float localE = 0.f;
        #pragma unroll
        for (int i = 0; i < 16; i++) {
            float evi = (i < 8) ? (float)e0[i & 7] : (float)e1[i & 7];
            localE += evi * avc[i];
        }
        float incE = localE;
        #pragma unroll
        for (int o = 1; o < 64; o <<= 1) { float vE = __shfl_up(incE, o); if (lane >= o) incE += vE; }
        if (lane == 63) wsumE[w] = incE;
        __syncthreads();
        float woffE = 0.f;
        for (int i = 0; i < w; i++) woffE += wsumE[i];
        const float U = wsumE[0] + wsumE[1] + wsumE[2] + wsumE[3];
        float runE = woffE + incE - localE;
        float eprev = (t > 0) ? (float)es[j0 - 1] : 0.f;
        float bprev = (t > 0) ? bv[j0 - 1] : 0.f;
        float bvc[16];
        #pragma unroll
        for (int i = 0; i < 16; i += 4) {
            float4 b4 = *(const float4*)(bv + j0 + i);
            bvc[i] = b4.x; bvc[i + 1] = b4.y; bvc[i + 2] = b4.z; bvc[i + 3] = b4.w;
        }
        bf16x8 o0, o1;
        float pE = eprev, pB = bprev;
        #pragma unroll
        for (int i = 0; i < 16; i++) {
            float evi = (i < 8) ? (float)e0[i & 7] : (float)e1[i & 7];
            float Tj = U - runE;
            runE += evi * avc[i];
            float pw = pE * pB;
            float l = Tj - pw;
            if (i < 8) o0[i & 7] = (__bf16)l; else o1[i & 7] = (__bf16)l;
            pE = evi; pB = bvc[i];
        }
        *(bf16x8*)(encPsiB + (size_t)h * DC + j0)     = o0;
        *(bf16x8*)(encPsiB + (size_t)h * DC + j0 + 8) = o1;
    }
}

// ---- combo2: cap [0,16) first + z_mean/etaW GEMMs [16,528) (BK=64, split-K 4) ----
// GEMM: XOR-chunk-swizzled LDS (rule #21). Epilogue writes per-slice PARTIALS
// with plain stores (no device-scope atomics); mfma_quad sums the 4 slices.
__global__ __launch_bounds__(256) void k_combo2(
    const __bf16* __restrict__ clrB, const __bf16* __restrict__ etaB,
    const __bf16* __restrict__ encPsiB, const __bf16* __restrict__ decWT,
    float* __restrict__ part,
    const float* __restrict__ WtW, const float* __restrict__ Dv,
    const float* __restrict__ scal, __bf16* __restrict__ WtWB,
    __bf16* __restrict__ MinvB, float* __restrict__ scal_out)
{
    __shared__ __bf16 As[64 * 64];    // 8 KB
    __shared__ __bf16 Bs[256 * 64];   // 32 KB
    const int tid = threadIdx.x;
    const int w = tid >> 6, lane = tid & 63;
    const int ln = lane & 15, q = lane >> 4;
    const int wm = w >> 1, wn = w & 1;
    const int bid = blockIdx.x;

    if (bid >= 16) {
        const int idx = bid - 16;
        const int g = idx >> 8, r = idx & 255, sl = r >> 6, mt = r & 63;
        const __bf16* A  = g ? etaB  : clrB;
        const __bf16* Bt = g ? decWT : encPsiB;
        float* C = part + ((size_t)(g * 4 + sl) << 20);   // this block's partial slice
        const int m0 = mt * 64, kb = sl * 1024;
        f32x4 acc[2][8] = {};
        for (int k0 = kb; k0 < kb + 1024; k0 += 64) {
            #pragma unroll
            for (int j = 0; j < 2; j++) {
                int c = j * 256 + tid;
                int row = c >> 3, ch = c & 7;
                async16(A + (size_t)(m0 + row) * DC + k0 + (ch ^ (row & 7)) * 8, As + c * 8);
            }
            #pragma unroll
            for (int j = 0; j < 8; j++) {
                int c = j * 256 + tid;
                int row = c >> 3, ch = c & 7;
                async16(Bt + (size_t)row * DC + k0 + (ch ^ (row & 7)) * 8, Bs + c * 8);
            }
            __syncthreads();
            #pragma unroll
            for (int jj = 0; jj < 2; jj++) {
                bf16x8 af[2], bfr[8];
                #pragma unroll
                for (int i = 0; i < 2; i++) {
                    int arow = wm * 32 + i * 16 + ln;
                    af[i]  = *(const bf16x8*)(As + arow * 64 + ((jj * 4 + q) ^ (arow & 7)) * 8);
                }
                #pragma unroll
                for (int i = 0; i < 8; i++) {
                    int brow = wn * 128 + i * 16 + ln;
                    bfr[i] = *(const bf16x8*)(Bs + brow * 64 + ((jj * 4 + q) ^ (brow & 7)) * 8);
                }
                #pragma unroll
                for (int mi = 0; mi < 2; mi++)
                    #pragma unroll
                    for (int ni = 0; ni < 8; ni++)
                        acc[mi][ni] = __builtin_amdgcn_mfma_f32_16x16x32_bf16(af[mi], bfr[ni], acc[mi][ni], 0, 0, 0);
            }
            __syncthreads();
        }
        #pragma unroll
        for (int mi = 0; mi < 2; mi++)
            #pragma unroll
            for (int rr = 0; rr < 4; rr++) {
                int m = m0 + wm * 32 + mi * 16 + q * 4 + rr;
                #pragma unroll
                for (int ni = 0; ni < 8; ni++) {
                    int n = wn * 128 + ni * 16 + ln;
                    C[(size_t)m * HID + n] = acc[mi][ni][rr];
                }
            }
    } else {
        // ---- cap: B2 = B@B (64x64 tile); Minv = (I - B + B2)*diag(Dv); traces ----
        __shared__ float dvs[HID];
        __shared__ float redc[8];
        const int w2 = bid;
        const int m0 = (w2 >> 2) * 64, n0 = (w2 & 3) * 64;
        dvs[tid] = Dv[tid];
        __syncthreads();
        const float rv = 1.f / scal[0];
        f32x4 acc[2][2] = {};
        for (int k0 = 0; k0 < HID; k0 += 32) {
            {
                int row = tid >> 2, kc = tid & 3;
                const float* srcA = WtW + (size_t)(m0 + row) * HID + k0 + kc * 8;
                const float* srcB = WtW + (size_t)(n0 + row) * HID + k0 + kc * 8;
                float sA = dvs[m0 + row] * rv;
                bf16x8 a8, b8;
                #pragma unroll
                for (int u = 0; u < 8; u++) {
                    a8[u] = (__bf16)(srcA[u] * sA);
                    b8[u] = (__bf16)(srcB[u] * dvs[k0 + kc * 8 + u] * rv);
                }
                *(bf16x8*)(As + tid * 8) = a8;
                *(bf16x8*)(Bs + tid * 8) = b8;
            }
            __syncthreads();
            bf16x8 af[2], bfr[2];
            #pragma unroll
            for (int i = 0; i < 2; i++) {
                af[i]  = *(const bf16x8*)(As + (wm * 32 + i * 16 + ln) * 32 + q * 8);
                bfr[i] = *(const bf16x8*)(Bs + (wn * 32 + i * 16 + ln) * 32 + q * 8);
            }
            #pragma unroll
            for (int mi = 0; mi < 2; mi++)
                #pragma unroll
                for (int ni = 0; ni < 2; ni++)
                    acc[mi][ni] = __builtin_amdgcn_mfma_f32_16x16x32_bf16(af[mi], bfr[ni], acc[mi][ni], 0, 0, 0);
            __syncthreads();
        }
        float t1p = 0.f, t2p = 0.f;
        #pragma unroll
        for (int mi = 0; mi < 2; mi++)
            #pragma unroll
            for (int rr = 0; rr < 4; rr++) {
                int m = m0 + wm * 32 + mi * 16 + q * 4 + rr;
                #pragma unroll
                for (int ni = 0; ni < 2; ni++) {
                    int n = n0 + wn * 32 + ni * 16 + ln;
                    float wmn = WtW[(size_t)m * HID + n];
                    float Bmn = dvs[m] * wmn * rv;
                    float Bnm = dvs[n] * wmn * rv;
                    float mv = (((m == n) ? 1.f : 0.f) - Bmn + acc[mi][ni][rr]) * dvs[n];
                    MinvB[(size_t)m * HID + n] = (__bf16)mv;
                    WtWB[(size_t)m * HID + n] = (__bf16)wmn;
                    t2p += Bmn * Bnm;
                    if (m == n) t1p += Bmn;
                }
            }
        for (int o = 32; o > 0; o >>= 1) { t1p += __shfl_down(t1p, o); t2p += __shfl_down(t2p, o); }
        if (lane == 0) { redc[w] = t1p; redc[4 + w] = t2p; }
        __syncthreads();
        if (tid == 0) {
            atomicAdd(&scal_out[2], redc[0] + redc[1] + redc[2] + redc[3]);
            atomicAdd(&scal_out[3], redc[4] + redc[5] + redc[6] + redc[7]);
        }
    }
}

// ---- fused quad: Zw = z@WtW, dW in LDS, T = dW@Minv, row dots; 16-row tiles ----
// z_mean/etaW are read as the sum of 4 split-K partial slices (part[0..3]=z,
// part[4..7]=etaW). 64B-stride tiles swizzled with chunk ^= (row>>1)&3.
__global__ __launch_bounds__(256) void mfma_quad(
    const float* __restrict__ part,
    const __bf16* __restrict__ WtWB, const __bf16* __restrict__ MinvB,
    float* __restrict__ r0a, float* __restrict__ r1a, float* __restrict__ r2a,
    float* __restrict__ r3a)
{
    __shared__ __bf16 As[16 * 32];
    __shared__ __bf16 Bs[256 * 32];
    __shared__ __bf16 dWs[16 * 264];
    const int tid = threadIdx.x;
    const int w = tid >> 6, lane = tid & 63;
    const int ln = lane & 15, q = lane >> 4;
    const int m0 = blockIdx.x * 16;
    const float* zp = part;
    const float* ep = part + ((size_t)4 << 20);
    const size_t SL = (size_t)1 << 20;

    f32x4 acc[4] = {};
    for (int k0 = 0; k0 < HID; k0 += 32) {
        {
            int row = tid >> 4, kc = tid & 15;
            size_t off = (size_t)(m0 + row) * HID + k0 + kc * 2;
            float2 v0 = *(const float2*)(zp + off);
            float2 v1 = *(const float2*)(zp + SL + off);
            float2 v2 = *(const float2*)(zp + 2 * SL + off);
            float2 v3 = *(const float2*)(zp + 3 * SL + off);
            float vx = v0.x + v1.x + v2.x + v3.x;
            float vy = v0.y + v1.y + v2.y + v3.y;
            bf16x2 b2 = {(__bf16)vx, (__bf16)vy};
            int ch = kc >> 2, wi = kc & 3;
            *(bf16x2*)(As + row * 32 + ((ch ^ ((row >> 1) & 3)) * 8) + wi * 2) = b2;
        }
        #pragma unroll
        for (int j = 0; j < 4; j++) {
            int c = j * 256 + tid;
            int row = c >> 2, ch = c & 3;
            async16(WtWB + (size_t)row * HID + k0 + (ch ^ ((row >> 1) & 3)) * 8, Bs + c * 8);
        }
        __syncthreads();
        bf16x8 af = *(const bf16x8*)(As + ln * 32 + ((q ^ ((ln >> 1) & 3)) * 8));
        #pragma unroll
        for (int ni = 0; ni < 4; ni++) {
            int brow = w * 64 + ni * 16 + ln;
            bf16x8 bfr = *(const bf16x8*)(Bs + brow * 32 + ((q ^ ((ln >> 1) & 3)) * 8));
            acc[ni] = __builtin_amdgcn_mfma_f32_16x16x32_bf16(af, bfr, acc[ni], 0, 0, 0);
        }
        __syncthreads();
    }
    #pragma unroll
    for (int rr = 0; rr < 4; rr++) {
        int lm = q * 4 + rr;
        int m = m0 + lm;
        float s0 = 0.f, s1 = 0.f, s3 = 0.f;
        #pragma unroll
        for (int ni = 0; ni < 4; ni++) {
            int n = w * 64 + ni * 16 + ln;
            size_t o2 = (size_t)m * HID + n;
            float zv = zp[o2] + zp[SL + o2] + zp[2 * SL + o2] + zp[3 * SL + o2];
            float ew = ep[o2] + ep[SL + o2] + ep[2 * SL + o2] + ep[3 * SL + o2];
            float dv = ew - acc[ni][rr];
            dWs[lm * 264 + n] = (__bf16)dv;
            s0 += ew * zv; s1 += dv * zv; s3 += zv * zv;
        }
        #pragma unroll
        for (int o = 1; o < 16; o <<= 1) {
            s0 += __shfl_xor(s0, o); s1 += __shfl_xor(s1, o); s3 += __shfl_xor(s3, o);
        }
        if (ln == 0) {
            atomicAdd(&r0a[m], s0); atomicAdd(&r1a[m], s1); atomicAdd(&r3a[m], s3);
        }
    }

    f32x4 acc2[4] = {};
    for (int k0 = 0; k0 < HID; k0 += 32) {
        #pragma unroll
        for (int j = 0; j < 4; j++) {
            int c = j * 256 + tid;
            int row = c >> 2, ch = c & 3;
            async16(MinvB + (size_t)row * HID + k0 + (ch ^ ((row >> 1) & 3)) * 8, Bs + c * 8);
        }
        __syncthreads();
        bf16x8 af = *(const bf16x8*)(dWs + ln * 264 + k0 + q * 8);
        #pragma unroll
        for (int ni = 0; ni < 4; ni++) {
            int brow = w * 64 + ni * 16 + ln;
            bf16x8 bfr = *(const bf16x8*)(Bs + brow * 32 + ((q ^ ((ln >> 1) & 3)) * 8));
            acc2[ni] = __builtin_amdgcn_mfma_f32_16x16x32_bf16(af, bfr, acc2[ni], 0, 0, 0);
        }
        __syncthreads();
    }
    #pragma unroll
    for (int rr = 0; rr < 4; rr++) {
        int lm = q * 4 + rr;
        int m = m0 + lm;
        float s2 = 0.f;
        #pragma unroll
        for (int ni = 0; ni < 4; ni++) {
            int n = w * 64 + ni * 16 + ln;
            s2 += (float)dWs[lm * 264 + n] * acc2[ni][rr];
        }
        #pragma unroll
        for (int o = 1; o < 16; o <<= 1) s2 += __shfl_xor(s2, o);
        if (ln == 0) atomicAdd(&r2a[m], s2);
    }
}

// ---- final assembly ----
__global__ void k_final(const float* __restrict__ multv, const float* __restrict__ eta2,
                        const float* __restrict__ r0a, const float* __restrict__ r1a,
                        const float* __restrict__ r2a, const float* __restrict__ r3a,
                        const float* __restrict__ scal, const float* __restrict__ lss,
                        float* __restrict__ out) {
    int t = threadIdx.x;
    float var = scal[0];
    float rv = 1.f / var;
    double am = 0.0, aq = 0.0, az = 0.0;
    for (int b = t; b < BB; b += 256) {
        am += (double)multv[b];
        aq += (double)((eta2[b] - r0a[b] - r1a[b]) * rv - r2a[b] * rv * rv);
        az += (double)r3a[b];
    }
    for (int o = 32; o > 0; o >>= 1) {
        am += __shfl_down(am, o); aq += __shfl_down(aq, o); az += __shfl_down(az, o);
    }
    __shared__ double red[3][4];
    if ((t & 63) == 0) { int w = t >> 6; red[0][w] = am; red[1][w] = aq; red[2][w] = az; }
    __syncthreads();
    if (t == 0) {
        double mm = (red[0][0] + red[0][1] + red[0][2] + red[0][3]) / (double)BB;
        double mq = (red[1][0] + red[1][1] + red[1][2] + red[1][3]) / (double)BB;
        double mz = (red[2][0] + red[2][1] + red[2][2] + red[2][3]) / ((double)BB * (double)HID);
        double t1 = scal[2], t2 = scal[3];
        double logdetIB = t1 - t2 * 0.5;
        double sumlv = (double)scal[1];
        double logdetM = -sumlv + logdetIB;
        double logdet_sigma = (double)NM1 * (double)lss[0] + sumlv + logdetM;
        double logit_loss = -0.5 * ((double)NM1 * LOG2PI_D + logdet_sigma + mq);
        double prior_loss = -0.5 * mz - 0.5 * LOG2PI_D;
        out[0] = (float)(-(mm + logit_loss + prior_loss));
    }
}

// ---------------- launcher ----------------

extern "C" void kernel_launch(void* const* d_in, const int* in_sizes, int n_in,
                              void* d_out, int out_size, void* d_ws, size_t ws_size,
                              hipStream_t stream) {
    (void)in_sizes; (void)n_in; (void)out_size; (void)ws_size;
    const float* x    = (const float*)d_in[0];
    const float* Psi  = (const float*)d_in[1];
    const float* encW = (const float*)d_in[2];
    const float* decW = (const float*)d_in[3];
    const float* lv   = (const float*)d_in[4];
    const float* lss  = (const float*)d_in[5];
    const float* eta  = (const float*)d_in[6];
    float* out = (float*)d_out;

    float* wp = (float*)d_ws;
    // --- split-K partials: z slices [0,4), etaW slices [4,8), 1M floats each ---
    float* part   = wp;                      // 8M floats = 32 MB (fully overwritten)
    // --- contiguous memset region (atomic targets) ---
    float* WtW    = part + ((size_t)8 << 20); // 64K
    float* r0a    = WtW    + 65536;          // 4K each
    float* r1a    = r0a    + 4096;
    float* r2a    = r1a    + 4096;
    float* r3a    = r2a    + 4096;
    float* scal   = r3a    + 4096;           // 16
    // --- rest ---
    float* av     = scal   + 16;
    float* bv     = av     + 4096;
    float* multv  = bv     + 4096;
    float* eta2   = multv  + 4096;
    float* Dv     = eta2   + 4096;           // 256
    __bf16* clrB    = (__bf16*)(Dv + 256);
    __bf16* etaB    = clrB    + (1 << 24);
    __bf16* encPsiB = etaB    + (1 << 24);   // 1M
    __bf16* decWT   = encPsiB + (1 << 20);   // 1M
    __bf16* WtWB    = decWT   + (1 << 20);   // 64K each
    __bf16* MinvB   = WtWB    + 65536;

    hipMemsetAsync(WtW, 0, (size_t)(65536 + 4 * 4096 + 16) * sizeof(float), stream);

    k_pre<<<1041, 256, 0, stream>>>(decW, Psi, lv, lss, decWT, av, bv, Dv, scal);

    k_wtw<<<256, 256, 0, stream>>>(decWT, WtW);

    k_rows<<<256 + BB, 256, 0, stream>>>(x, eta, encW, av, bv,
                                         multv, eta2, clrB, etaB, encPsiB);

    k_combo2<<<528, 256, 0, stream>>>(clrB, etaB, encPsiB, decWT, part,
                                      WtW, Dv, scal, WtWB, MinvB, scal);

    mfma_quad<<<256, 256, 0, stream>>>(part, WtWB, MinvB, r0a, r1a, r2a, r3a);

    k_final<<<1, 256, 0, stream>>>(multv, eta2, r0a, r1a, r2a, r3a, scal, lss, out);
}

// Round 12
// 286.564 us; speedup vs baseline: 1.1641x; 1.0188x over previous
//
#include <hip/hip_runtime.h>
#include <math.h>

static constexpr int DC  = 4096;   // D_CAT
static constexpr int NM1 = 4095;   // D_CAT - 1
static constexpr int HID = 256;
static constexpr int BB  = 4096;   // batch
static constexpr double LOG2PI_D = 1.8378770664093454835;

typedef __attribute__((ext_vector_type(8))) __bf16 bf16x8;
typedef __attribute__((ext_vector_type(4))) __bf16 bf16x4;
typedef __attribute__((ext_vector_type(2))) __bf16 bf16x2;
typedef __attribute__((ext_vector_type(4))) float  f32x4;

__device__ __forceinline__ void async16(const __bf16* g, __bf16* l) {
    __builtin_amdgcn_global_load_lds(
        (const __attribute__((address_space(1))) void*)g,
        (__attribute__((address_space(3))) void*)l, 16, 0, 0);
}

// ---- pre: decW transpose [0,1024) + Helmert coeffs [1024,1040) + scalars (1040) ----
__global__ __launch_bounds__(256) void k_pre(
    const float* __restrict__ decW, const float* __restrict__ Psi,
    const float* __restrict__ lv, const float* __restrict__ lss,
    __bf16* __restrict__ decWT, float* __restrict__ av, float* __restrict__ bv,
    float* __restrict__ Dv, float* __restrict__ scal)
{
    __shared__ float tp[32][33];
    const int t = threadIdx.x;
    const int blk = blockIdx.x;
    if (blk < 1024) {
        int bx = blk & 7, by = blk >> 3;
        int tx = t & 31, ty = t >> 5;
        int r0 = by * 32, c0 = bx * 32;
        #pragma unroll
        for (int i = 0; i < 4; i++) {
            int r = r0 + ty + i * 8, c = c0 + tx;
            tp[ty + i * 8][tx] = (r < NM1 && c < HID) ? decW[(size_t)r * HID + c] : 0.f;
        }
        __syncthreads();
        #pragma unroll
        for (int i = 0; i < 4; i++) {
            int c = c0 + ty + i * 8, r = r0 + tx;
            decWT[(size_t)c * DC + r] = (__bf16)tp[tx][ty + i * 8];
        }
    } else if (blk < 1040) {
        int r = (blk - 1024) * 256 + t;
        if (r < NM1) {
            av[r] = Psi[(size_t)r * DC];
            bv[r] = -Psi[(size_t)r * DC + r + 1];
        } else { av[r] = 0.f; bv[r] = 0.f; }
    } else {
        float v = lv[t];
        Dv[t] = expf(v);
        for (int o = 32; o > 0; o >>= 1) v += __shfl_down(v, o);
        __shared__ float red[4];
        if ((t & 63) == 0) red[t >> 6] = v;
        __syncthreads();
        if (t == 0) {
            scal[0] = expf(lss[0]);
            scal[1] = red[0] + red[1] + red[2] + red[3];
        }
    }
}

// ---- mega: WtW gemm [0,64) + encscan [64,320) + rows [320, 320+BB) ----
// Rows are barrier-minimized: (1) per-wave LUT (same-wave LDS write->read
// needs no barrier) kills B0; (2) clrB/etaB stores issued AFTER the last
// barrier so no __syncthreads (which drains vmcnt(0)) waits on stores;
// (3) avc+bvc issued post-B1 to overlap scan1. 3 barriers total (was 4),
// and only ONE barrier (B1) waits on global-load latency.
__global__ __launch_bounds__(256) void k_mega(
    const float* __restrict__ x, const float* __restrict__ eta,
    const float* __restrict__ encW, const __bf16* __restrict__ decWT,
    const float* __restrict__ av, const float* __restrict__ bv,
    float* __restrict__ multv, float* __restrict__ eta2,
    __bf16* __restrict__ clrB, __bf16* __restrict__ etaB,
    __bf16* __restrict__ encPsiB, float* __restrict__ WtW)
{
    __shared__ float smemf[2592];
    const int t = threadIdx.x;
    const int blk = blockIdx.x;
    const int lane = t & 63, w = t >> 6;

    if (blk >= 64 + HID) {
        __bf16* es    = (__bf16*)smemf;          // [4096] bf16 = 2048 floats
        float* red    = smemf + 2048;            // [24]
        float* wsumE  = smemf + 2072;            // [4]
        float* wsumX  = smemf + 2076;            // [4]
        float* firstX = smemf + 2080;            // [256]
        float* lutL   = smemf + 2336;            // [128] = 4 waves x 32
        float* lutG   = smemf + 2464;            // [128]
        const int b = blk - (64 + HID);
        const int j0 = t * 16;

        // P0: x contiguous per-thread loads (row base 16B-aligned)
        const float4* xrow = (const float4*)(x + (size_t)b * DC + j0);
        float4 xq[4];
        #pragma unroll
        for (int i = 0; i < 4; i++) xq[i] = xrow[i];

        // eta strided loads
        const float* erow = eta + (size_t)b * NM1;
        float ee[16];
        #pragma unroll
        for (int i = 0; i < 16; i++) { int j = i * 256 + t; ee[i] = (j < NM1) ? erow[j] : 0.f; }

        // per-wave LUT: no barrier needed (same-wave LDS ordering)
        float* lutLw = lutL + w * 32;
        float* lutGw = lutG + w * 32;
        if (lane < 32) { float f = (float)lane + 1.f; lutLw[lane] = logf(f); lutGw[lane] = lgammaf(f); }

        // stats over x; pack x to bf16 (counts 0..19 -> exact)
        bf16x8 xp0, xp1;
        float s = 0.f, slg = 0.f, slp = 0.f;
        {
            float xv[16];
            #pragma unroll
            for (int i = 0; i < 4; i++) {
                xv[i * 4 + 0] = xq[i].x; xv[i * 4 + 1] = xq[i].y;
                xv[i * 4 + 2] = xq[i].z; xv[i * 4 + 3] = xq[i].w;
            }
            #pragma unroll
            for (int i = 0; i < 16; i++) {
                float vf = xv[i];
                int iv = (int)vf;
                float l, g;
                if (vf == (float)iv && iv >= 0 && iv < 32) { l = lutLw[iv]; g = lutGw[iv]; }
                else { l = logf(vf + 1.f); g = lgammaf(vf + 1.f); }
                s += vf; slg += g; slp += l;
            }
            #pragma unroll
            for (int i = 0; i < 8; i++) { xp0[i] = (__bf16)xv[i]; xp1[i] = (__bf16)xv[i + 8]; }
            firstX[t] = xv[0];
        }
        // e2 + es (bf16) writes from strided eta regs
        float e2 = 0.f;
        #pragma unroll
        for (int i = 0; i < 16; i++) {
            float e = ee[i];
            e2 += e * e;
            es[i * 256 + t] = (__bf16)e;
        }
        for (int o = 32; o > 0; o >>= 1) {
            s += __shfl_down(s, o); slg += __shfl_down(slg, o);
            slp += __shfl_down(slp, o); e2 += __shfl_down(e2, o);
        }
        if (lane == 0) { red[w] = s; red[4 + w] = slg; red[8 + w] = slp; red[12 + w] = e2; }
        __syncthreads();   // B1: red + es + firstX visible (loads already consumed)

        const float m = (red[8] + red[9] + red[10] + red[11]) * (1.f / DC);

        // avc + bvc (L2-resident) issued together; latency overlaps scan1
        float avc[16], bvc[16];
        #pragma unroll
        for (int i = 0; i < 16; i += 4) {
            float4 a4 = *(const float4*)(av + j0 + i);
            avc[i] = a4.x; avc[i + 1] = a4.y; avc[i + 2] = a4.z; avc[i + 3] = a4.w;
            float4 b4 = *(const float4*)(bv + j0 + i);
            bvc[i] = b4.x; bvc[i + 1] = b4.y; bvc[i + 2] = b4.z; bvc[i + 3] = b4.w;
        }

        // eta (bf16, packed) kept in regs for the scan; stored at kernel end
        bf16x8 e0 = *(const bf16x8*)(es + j0);
        bf16x8 e1 = *(const bf16x8*)(es + j0 + 8);

        // scan pass 1
        float localE = 0.f, localX = 0.f;
        #pragma unroll
        for (int i = 0; i < 16; i++) {
            float evi = (i < 8) ? (float)e0[i & 7] : (float)e1[i & 7];
            float xvi = (i < 8) ? (float)xp0[i & 7] : (float)xp1[i & 7];
            localE += evi * avc[i]; localX += xvi;
        }
        float incE = localE, incX = localX;
        #pragma unroll
        for (int o = 1; o < 64; o <<= 1) {
            float vE = __shfl_up(incE, o), vX = __shfl_up(incX, o);
            if (lane >= o) { incE += vE; incX += vX; }
        }
        if (lane == 63) { wsumE[w] = incE; wsumX[w] = incX; }
        __syncthreads();   // B2: wsum visible (no stores outstanding)

        float woffE = 0.f, woffX = 0.f;
        for (int i = 0; i < w; i++) { woffE += wsumE[i]; woffX += wsumX[i]; }
        const float U = wsumE[0] + wsumE[1] + wsumE[2] + wsumE[3];
        float runE = woffE + incE - localE;
        float Xrun = woffX + incX - localX;

        float eprev = (t > 0) ? (float)es[j0 - 1] : 0.f;
        float bprev = (t > 0) ? bv[j0 - 1] : 0.f;
        float xnl   = (t < 255) ? firstX[t + 1] : 0.f;

        float se = 0.f, sx = 0.f;
        float pE = eprev, pB = bprev;   // carry: ev[i-1], bvc[i-1]
        #pragma unroll
        for (int i = 0; i < 16; i++) {
            float evi = (i < 8) ? (float)e0[i & 7] : (float)e1[i & 7];
            float xvi = (i < 8) ? (float)xp0[i & 7] : (float)xp1[i & 7];
            float Tj = U - runE;
            runE += evi * avc[i];
            float pw = pE * pB;
            float l = Tj - pw;
            se += expf(l);
            Xrun += xvi;
            float xn = (i < 15) ? ((i + 1 < 8) ? (float)xp0[(i + 1) & 7] : (float)xp1[(i + 1) & 7]) : xnl;
            sx += evi * (avc[i] * Xrun - bvc[i] * xn);
            pE = evi; pB = bvc[i];
        }
        for (int o = 32; o > 0; o >>= 1) {
            se += __shfl_down(se, o); sx += __shfl_down(sx, o);
        }
        if (lane == 0) { red[16 + w] = se; red[20 + w] = sx; }
        __syncthreads();   // B3 (no outstanding vmem)
        if (t == 0) {
            float ntotv  = red[0] + red[1] + red[2] + red[3];
            float sumlgv = red[4] + red[5] + red[6] + red[7];
            float S1t = red[16] + red[17] + red[18] + red[19];
            float S2t = red[20] + red[21] + red[22] + red[23];
            float e2t = red[12] + red[13] + red[14] + red[15];
            double mult = (double)lgammaf(ntotv + 1.f) - (double)sumlgv
                        + (double)S2t - (double)ntotv * (double)logf(S1t);
            multv[b] = (float)mult;
            eta2[b]  = e2t;
        }

        // ---- stores at the very end: no barrier ever waits on them ----
        *(bf16x8*)(etaB + (size_t)b * DC + j0)     = e0;
        *(bf16x8*)(etaB + (size_t)b * DC + j0 + 8) = e1;
        {
            // recompute clr from packed x + block-uniform m (identical exprs;
            // LUT region untouched since the stats phase)
            bf16x8 c0, c1;
            #pragma unroll
            for (int i = 0; i < 16; i++) {
                float vf = (i < 8) ? (float)xp0[i & 7] : (float)xp1[i & 7];
                int iv = (int)vf;
                float l = (vf == (float)iv && iv >= 0 && iv < 32) ? lutLw[iv] : logf(vf + 1.f);
                if (i < 8) c0[i & 7] = (__bf16)(l - m); else c1[i & 7] = (__bf16)(l - m);
            }
            *(bf16x8*)(clrB + (size_t)b * DC + j0)     = c0;
            *(bf16x8*)(clrB + (size_t)b * DC + j0 + 8) = c1;
        }
    } else if (blk >= 64) {
        // ---------------- encscan ----------------
        __bf16* es   = (__bf16*)smemf;
        float* wsumE = smemf + 2048;
        const int h = blk - 64;
        const float* erow = encW + (size_t)h * NM1;
        {
            float ee[16];
            #pragma unroll
            for (int i = 0; i < 16; i++) { int j = i * 256 + t; ee[i] = (j < NM1) ? erow[j] : 0.f; }
            #pragma unroll
            for (int i = 0; i < 16; i++) es[i * 256 + t] = (__bf16)ee[i];
        }
        const int j0 = t * 16;
        float avc[16];
        #pragma unroll
        for (int i = 0; i < 16; i += 4) {
            float4 a4 = *(const float4*)(av + j0 + i);
            avc[i] = a4.x; avc[i + 1] = a4.y; avc[i + 2] = a4.z; avc[i + 3] = a4.w;
        }
        __syncthreads();
        bf16x8 e0 = *(const bf16x8*)(es + j0);
        bf16x8 e1 = *(const bf16x8*)(es + j0 + 8);
        float localE = 0.f;
        #pragma unroll
        for (int i = 0; i < 16; i++) {
            float evi = (i < 8) ? (float)e0[i & 7] : (float)e1[i & 7];
            localE += evi * avc[i];
        }
        float incE = localE;
        #pragma unroll
        for (int o = 1; o < 64; o <<= 1) { float vE = __shfl_up(incE, o); if (lane >= o) incE += vE; }
        if (lane == 63) wsumE[w] = incE;
        __syncthreads();
        float woffE = 0.f;
        for (int i = 0; i < w; i++) woffE += wsumE[i];
        const float U = wsumE[0] + wsumE[1] + wsumE[2] + wsumE[3];
        float runE = woffE + incE - localE;
        float eprev = (t > 0) ? (float)es[j0 - 1] : 0.f;
        float bprev = (t > 0) ? bv[j0 - 1] : 0.f;
        float bvc[16];
        #pragma unroll
        for (int i = 0; i < 16; i += 4) {
            float4 b4 = *(const float4*)(bv + j0 + i);
            bvc[i] = b4.x; bvc[i + 1] = b4.y; bvc[i + 2] = b4.z; bvc[i + 3] = b4.w;
        }
        bf16x8 o0, o1;
        float pE = eprev, pB = bprev;
        #pragma unroll
        for (int i = 0; i < 16; i++) {
            float evi = (i < 8) ? (float)e0[i & 7] : (float)e1[i & 7];
            float Tj = U - runE;
            runE += evi * avc[i];
            float pw = pE * pB;
            float l = Tj - pw;
            if (i < 8) o0[i & 7] = (__bf16)l; else o1[i & 7] = (__bf16)l;
            pE = evi; pB = bvc[i];
        }
        *(bf16x8*)(encPsiB + (size_t)h * DC + j0)     = o0;
        *(bf16x8*)(encPsiB + (size_t)h * DC + j0 + 8) = o1;
    } else {
        // ---------------- WtW = decWT @ decWT^T, 64x64 tiles x 4 K-slices ----------------
        __bf16* As = (__bf16*)smemf;            // 64x32 = 4 KB
        __bf16* Bs = (__bf16*)(smemf + 1024);   // 64x32 = 4 KB
        const int w2 = blk;                     // 0..63
        const int mn = w2 & 15, sl = w2 >> 4;
        const int m0 = (mn >> 2) * 64, n0 = (mn & 3) * 64, kb = sl * 1024;
        const int ln = lane & 15, q = lane >> 4;
        const int wm = w >> 1, wn = w & 1;
        f32x4 acc[2][2] = {};
        for (int k0 = kb; k0 < kb + 1024; k0 += 32) {
            async16(decWT + (size_t)(m0 + (t >> 2)) * DC + k0 + (t & 3) * 8, As + t * 8);
            async16(decWT + (size_t)(n0 + (t >> 2)) * DC + k0 + (t & 3) * 8, Bs + t * 8);
            __syncthreads();
            bf16x8 af[2], bfr[2];
            #pragma unroll
            for (int i = 0; i < 2; i++) {
                af[i]  = *(const bf16x8*)(As + (wm * 32 + i * 16 + ln) * 32 + q * 8);
                bfr[i] = *(const bf16x8*)(Bs + (wn * 32 + i * 16 + ln) * 32 + q * 8);
            }
            #pragma unroll
            for (int mi = 0; mi < 2; mi++)
                #pragma unroll
                for (int ni = 0; ni < 2; ni++)
                    acc[mi][ni] = __builtin_amdgcn_mfma_f32_16x16x32_bf16(af[mi], bfr[ni], acc[mi][ni], 0, 0, 0);
            __syncthreads();
        }
        #pragma unroll
        for (int mi = 0; mi < 2; mi++)
            #pragma unroll
            for (int rr = 0; rr < 4; rr++) {
                int m = m0 + wm * 32 + mi * 16 + q * 4 + rr;
                #pragma unroll
                for (int ni = 0; ni < 2; ni++)
                    atomicAdd(&WtW[(size_t)m * HID + n0 + wn * 32 + ni * 16 + ln], acc[mi][ni][rr]);
            }
    }
}

// ---- combo2: cap [0,16) first + z_mean/etaW GEMMs [16,528) (BK=64, split-K 4) ----
// GEMM: XOR-chunk-swizzled LDS (rule #21). Epilogue writes per-slice PARTIALS
// with plain stores (no device-scope atomics); mfma_quad sums the 4 slices.
__global__ __launch_bounds__(256) void k_combo2(
    const __bf16* __restrict__ clrB, const __bf16* __restrict__ etaB,
    const __bf16* __restrict__ encPsiB, const __bf16* __restrict__ decWT,
    float* __restrict__ part,
    const float* __restrict__ WtW, const float* __restrict__ Dv,
    const float* __restrict__ scal, __bf16* __restrict__ WtWB,
    __bf16* __restrict__ MinvB, float* __restrict__ scal_out)
{
    __shared__ __bf16 As[64 * 64];    // 8 KB
    __shared__ __bf16 Bs[256 * 64];   // 32 KB
    const int tid = threadIdx.x;
    const int w = tid >> 6, lane = tid & 63;
    const int ln = lane & 15, q = lane >> 4;
    const int wm = w >> 1, wn = w & 1;
    const int bid = blockIdx.x;

    if (bid >= 16) {
        const int idx = bid - 16;
        const int g = idx >> 8, r = idx & 255, sl = r >> 6, mt = r & 63;
        const __bf16* A  = g ? etaB  : clrB;
        const __bf16* Bt = g ? decWT : encPsiB;
        float* C = part + ((size_t)(g * 4 + sl) << 20);   // this block's partial slice
        const int m0 = mt * 64, kb = sl * 1024;
        f32x4 acc[2][8] = {};
        for (int k0 = kb; k0 < kb + 1024; k0 += 64) {
            #pragma unroll
            for (int j = 0; j < 2; j++) {
                int c = j * 256 + tid;
                int row = c >> 3, ch = c & 7;
                async16(A + (size_t)(m0 + row) * DC + k0 + (ch ^ (row & 7)) * 8, As + c * 8);
            }
            #pragma unroll
            for (int j = 0; j < 8; j++) {
                int c = j * 256 + tid;
                int row = c >> 3, ch = c & 7;
                async16(Bt + (size_t)row * DC + k0 + (ch ^ (row & 7)) * 8, Bs + c * 8);
            }
            __syncthreads();
            #pragma unroll
            for (int jj = 0; jj < 2; jj++) {
                bf16x8 af[2], bfr[8];
                #pragma unroll
                for (int i = 0; i < 2; i++) {
                    int arow = wm * 32 + i * 16 + ln;
                    af[i]  = *(const bf16x8*)(As + arow * 64 + ((jj * 4 + q) ^ (arow & 7)) * 8);
                }
                #pragma unroll
                for (int i = 0; i < 8; i++) {
                    int brow = wn * 128 + i * 16 + ln;
                    bfr[i] = *(const bf16x8*)(Bs + brow * 64 + ((jj * 4 + q) ^ (brow & 7)) * 8);
                }
                #pragma unroll
                for (int mi = 0; mi < 2; mi++)
                    #pragma unroll
                    for (int ni = 0; ni < 8; ni++)
                        acc[mi][ni] = __builtin_amdgcn_mfma_f32_16x16x32_bf16(af[mi], bfr[ni], acc[mi][ni], 0, 0, 0);
            }
            __syncthreads();
        }
        #pragma unroll
        for (int mi = 0; mi < 2; mi++)
            #pragma unroll
            for (int rr = 0; rr < 4; rr++) {
                int m = m0 + wm * 32 + mi * 16 + q * 4 + rr;
                #pragma unroll
                for (int ni = 0; ni < 8; ni++) {
                    int n = wn * 128 + ni * 16 + ln;
                    C[(size_t)m * HID + n] = acc[mi][ni][rr];
                }
            }
    } else {
        // ---- cap: B2 = B@B (64x64 tile); Minv = (I - B + B2)*diag(Dv); traces ----
        __shared__ float dvs[HID];
        __shared__ float redc[8];
        const int w2 = bid;
        const int m0 = (w2 >> 2) * 64, n0 = (w2 & 3) * 64;
        dvs[tid] = Dv[tid];
        __syncthreads();
        const float rv = 1.f / scal[0];
        f32x4 acc[2][2] = {};
        for (int k0 = 0; k0 < HID; k0 += 32) {
            {
                int row = tid >> 2, kc = tid & 3;
                const float* srcA = WtW + (size_t)(m0 + row) * HID + k0 + kc * 8;
                const float* srcB = WtW + (size_t)(n0 + row) * HID + k0 + kc * 8;
                float sA = dvs[m0 + row] * rv;
                bf16x8 a8, b8;
                #pragma unroll
                for (int u = 0; u < 8; u++) {
                    a8[u] = (__bf16)(srcA[u] * sA);
                    b8[u] = (__bf16)(srcB[u] * dvs[k0 + kc * 8 + u] * rv);
                }
                *(bf16x8*)(As + tid * 8) = a8;
                *(bf16x8*)(Bs + tid * 8) = b8;
            }
            __syncthreads();
            bf16x8 af[2], bfr[2];
            #pragma unroll
            for (int i = 0; i < 2; i++) {
                af[i]  = *(const bf16x8*)(As + (wm * 32 + i * 16 + ln) * 32 + q * 8);
                bfr[i] = *(const bf16x8*)(Bs + (wn * 32 + i * 16 + ln) * 32 + q * 8);
            }
            #pragma unroll
            for (int mi = 0; mi < 2; mi++)
                #pragma unroll
                for (int ni = 0; ni < 2; ni++)
                    acc[mi][ni] = __builtin_amdgcn_mfma_f32_16x16x32_bf16(af[mi], bfr[ni], acc[mi][ni], 0, 0, 0);
            __syncthreads();
        }
        float t1p = 0.f, t2p = 0.f;
        #pragma unroll
        for (int mi = 0; mi < 2; mi++)
            #pragma unroll
            for (int rr = 0; rr < 4; rr++) {
                int m = m0 + wm * 32 + mi * 16 + q * 4 + rr;
                #pragma unroll
                for (int ni = 0; ni < 2; ni++) {
                    int n = n0 + wn * 32 + ni * 16 + ln;
                    float wmn = WtW[(size_t)m * HID + n];
                    float Bmn = dvs[m] * wmn * rv;
                    float Bnm = dvs[n] * wmn * rv;
                    float mv = (((m == n) ? 1.f : 0.f) - Bmn + acc[mi][ni][rr]) * dvs[n];
                    MinvB[(size_t)m * HID + n] = (__bf16)mv;
                    WtWB[(size_t)m * HID + n] = (__bf16)wmn;
                    t2p += Bmn * Bnm;
                    if (m == n) t1p += Bmn;
                }
            }
        for (int o = 32; o > 0; o >>= 1) { t1p += __shfl_down(t1p, o); t2p += __shfl_down(t2p, o); }
        if (lane == 0) { redc[w] = t1p; redc[4 + w] = t2p; }
        __syncthreads();
        if (tid == 0) {
            atomicAdd(&scal_out[2], redc[0] + redc[1] + redc[2] + redc[3]);
            atomicAdd(&scal_out[3], redc[4] + redc[5] + redc[6] + redc[7]);
        }
    }
}

// ---- fused quad: Zw = z@WtW, dW in LDS, T = dW@Minv, row dots; 16-row tiles ----
// z_mean/etaW are read as the sum of 4 split-K partial slices (part[0..3]=z,
// part[4..7]=etaW). 64B-stride tiles swizzled with chunk ^= (row>>1)&3.
__global__ __launch_bounds__(256) void mfma_quad(
    const float* __restrict__ part,
    const __bf16* __restrict__ WtWB, const __bf16* __restrict__ MinvB,
    float* __restrict__ r0a, float* __restrict__ r1a, float* __restrict__ r2a,
    float* __restrict__ r3a)
{
    __shared__ __bf16 As[16 * 32];
    __shared__ __bf16 Bs[256 * 32];
    __shared__ __bf16 dWs[16 * 264];
    const int tid = threadIdx.x;
    const int w = tid >> 6, lane = tid & 63;
    const int ln = lane & 15, q = lane >> 4;
    const int m0 = blockIdx.x * 16;
    const float* zp = part;
    const float* ep = part + ((size_t)4 << 20);
    const size_t SL = (size_t)1 << 20;

    f32x4 acc[4] = {};
    for (int k0 = 0; k0 < HID; k0 += 32) {
        {
            int row = tid >> 4, kc = tid & 15;
            size_t off = (size_t)(m0 + row) * HID + k0 + kc * 2;
            float2 v0 = *(const float2*)(zp + off);
            float2 v1 = *(const float2*)(zp + SL + off);
            float2 v2 = *(const float2*)(zp + 2 * SL + off);
            float2 v3 = *(const float2*)(zp + 3 * SL + off);
            float vx = v0.x + v1.x + v2.x + v3.x;
            float vy = v0.y + v1.y + v2.y + v3.y;
            bf16x2 b2 = {(__bf16)vx, (__bf16)vy};
            int ch = kc >> 2, wi = kc & 3;
            *(bf16x2*)(As + row * 32 + ((ch ^ ((row >> 1) & 3)) * 8) + wi * 2) = b2;
        }
        #pragma unroll
        for (int j = 0; j < 4; j++) {
            int c = j * 256 + tid;
            int row = c >> 2, ch = c & 3;
            async16(WtWB + (size_t)row * HID + k0 + (ch ^ ((row >> 1) & 3)) * 8, Bs + c * 8);
        }
        __syncthreads();
        bf16x8 af = *(const bf16x8*)(As + ln * 32 + ((q ^ ((ln >> 1) & 3)) * 8));
        #pragma unroll
        for (int ni = 0; ni < 4; ni++) {
            int brow = w * 64 + ni * 16 + ln;
            bf16x8 bfr = *(const bf16x8*)(Bs + brow * 32 + ((q ^ ((ln >> 1) & 3)) * 8));
            acc[ni] = __builtin_amdgcn_mfma_f32_16x16x32_bf16(af, bfr, acc[ni], 0, 0, 0);
        }
        __syncthreads();
    }
    #pragma unroll
    for (int rr = 0; rr < 4; rr++) {
        int lm = q * 4 + rr;
        int m = m0 + lm;
        float s0 = 0.f, s1 = 0.f, s3 = 0.f;
        #pragma unroll
        for (int ni = 0; ni < 4; ni++) {
            int n = w * 64 + ni * 16 + ln;
            size_t o2 = (size_t)m * HID + n;
            float zv = zp[o2] + zp[SL + o2] + zp[2 * SL + o2] + zp[3 * SL + o2];
            float ew = ep[o2] + ep[SL + o2] + ep[2 * SL + o2] + ep[3 * SL + o2];
            float dv = ew - acc[ni][rr];
            dWs[lm * 264 + n] = (__bf16)dv;
            s0 += ew * zv; s1 += dv * zv; s3 += zv * zv;
        }
        #pragma unroll
        for (int o = 1; o < 16; o <<= 1) {
            s0 += __shfl_xor(s0, o); s1 += __shfl_xor(s1, o); s3 += __shfl_xor(s3, o);
        }
        if (ln == 0) {
            atomicAdd(&r0a[m], s0); atomicAdd(&r1a[m], s1); atomicAdd(&r3a[m], s3);
        }
    }

    f32x4 acc2[4] = {};
    for (int k0 = 0; k0 < HID; k0 += 32) {
        #pragma unroll
        for (int j = 0; j < 4; j++) {
            int c = j * 256 + tid;
            int row = c >> 2, ch = c & 3;
            async16(MinvB + (size_t)row * HID + k0 + (ch ^ ((row >> 1) & 3)) * 8, Bs + c * 8);
        }
        __syncthreads();
        bf16x8 af = *(const bf16x8*)(dWs + ln * 264 + k0 + q * 8);
        #pragma unroll
        for (int ni = 0; ni < 4; ni++) {
            int brow = w * 64 + ni * 16 + ln;
            bf16x8 bfr = *(const bf16x8*)(Bs + brow * 32 + ((q ^ ((ln >> 1) & 3)) * 8));
            acc2[ni] = __builtin_amdgcn_mfma_f32_16x16x32_bf16(af, bfr, acc2[ni], 0, 0, 0);
        }
        __syncthreads();
    }
    #pragma unroll
    for (int rr = 0; rr < 4; rr++) {
        int lm = q * 4 + rr;
        int m = m0 + lm;
        float s2 = 0.f;
        #pragma unroll
        for (int ni = 0; ni < 4; ni++) {
            int n = w * 64 + ni * 16 + ln;
            s2 += (float)dWs[lm * 264 + n] * acc2[ni][rr];
        }
        #pragma unroll
        for (int o = 1; o < 16; o <<= 1) s2 += __shfl_xor(s2, o);
        if (ln == 0) atomicAdd(&r2a[m], s2);
    }
}

// ---- final assembly ----
__global__ void k_final(const float* __restrict__ multv, const float* __restrict__ eta2,
                        const float* __restrict__ r0a, const float* __restrict__ r1a,
                        const float* __restrict__ r2a, const float* __restrict__ r3a,
                        const float* __restrict__ scal, const float* __restrict__ lss,
                        float* __restrict__ out) {
    int t = threadIdx.x;
    float var = scal[0];
    float rv = 1.f / var;
    double am = 0.0, aq = 0.0, az = 0.0;
    for (int b = t; b < BB; b += 256) {
        am += (double)multv[b];
        aq += (double)((eta2[b] - r0a[b] - r1a[b]) * rv - r2a[b] * rv * rv);
        az += (double)r3a[b];
    }
    for (int o = 32; o > 0; o >>= 1) {
        am += __shfl_down(am, o); aq += __shfl_down(aq, o); az += __shfl_down(az, o);
    }
    __shared__ double red[3][4];
    if ((t & 63) == 0) { int w = t >> 6; red[0][w] = am; red[1][w] = aq; red[2][w] = az; }
    __syncthreads();
    if (t == 0) {
        double mm = (red[0][0] + red[0][1] + red[0][2] + red[0][3]) / (double)BB;
        double mq = (red[1][0] + red[1][1] + red[1][2] + red[1][3]) / (double)BB;
        double mz = (red[2][0] + red[2][1] + red[2][2] + red[2][3]) / ((double)BB * (double)HID);
        double t1 = scal[2], t2 = scal[3];
        double logdetIB = t1 - t2 * 0.5;
        double sumlv = (double)scal[1];
        double logdetM = -sumlv + logdetIB;
        double logdet_sigma = (double)NM1 * (double)lss[0] + sumlv + logdetM;
        double logit_loss = -0.5 * ((double)NM1 * LOG2PI_D + logdet_sigma + mq);
        double prior_loss = -0.5 * mz - 0.5 * LOG2PI_D;
        out[0] = (float)(-(mm + logit_loss + prior_loss));
    }
}

// ---------------- launcher ----------------

extern "C" void kernel_launch(void* const* d_in, const int* in_sizes, int n_in,
                              void* d_out, int out_size, void* d_ws, size_t ws_size,
                              hipStream_t stream) {
    (void)in_sizes; (void)n_in; (void)out_size; (void)ws_size;
    const float* x    = (const float*)d_in[0];
    const float* Psi  = (const float*)d_in[1];
    const float* encW = (const float*)d_in[2];
    const float* decW = (const float*)d_in[3];
    const float* lv   = (const float*)d_in[4];
    const float* lss  = (const float*)d_in[5];
    const float* eta  = (const float*)d_in[6];
    float* out = (float*)d_out;

    float* wp = (float*)d_ws;
    // --- split-K partials: z slices [0,4), etaW slices [4,8), 1M floats each ---
    float* part   = wp;                      // 8M floats = 32 MB (fully overwritten)
    // --- contiguous memset region (atomic targets) ---
    float* WtW    = part + ((size_t)8 << 20); // 64K
    float* r0a    = WtW    + 65536;          // 4K each
    float* r1a    = r0a    + 4096;
    float* r2a    = r1a    + 4096;
    float* r3a    = r2a    + 4096;
    float* scal   = r3a    + 4096;           // 16
    // --- rest ---
    float* av     = scal   + 16;
    float* bv     = av     + 4096;
    float* multv  = bv     + 4096;
    float* eta2   = multv  + 4096;
    float* Dv     = eta2   + 4096;           // 256
    __bf16* clrB    = (__bf16*)(Dv + 256);
    __bf16* etaB    = clrB    + (1 << 24);
    __bf16* encPsiB = etaB    + (1 << 24);   // 1M
    __bf16* decWT   = encPsiB + (1 << 20);   // 1M
    __bf16* WtWB    = decWT   + (1 << 20);   // 64K each
    __bf16* MinvB   = WtWB    + 65536;

    hipMemsetAsync(WtW, 0, (size_t)(65536 + 4 * 4096 + 16) * sizeof(float), stream);

    k_pre<<<1041, 256, 0, stream>>>(decW, Psi, lv, lss, decWT, av, bv, Dv, scal);

    k_mega<<<64 + HID + BB, 256, 0, stream>>>(x, eta, encW, decWT, av, bv,
                                              multv, eta2, clrB, etaB, encPsiB, WtW);

    k_combo2<<<528, 256, 0, stream>>>(clrB, etaB, encPsiB, decWT, part,
                                      WtW, Dv, scal, WtWB, MinvB, scal);

    mfma_quad<<<256, 256, 0, stream>>>(part, WtWB, MinvB, r0a, r1a, r2a, r3a);

    k_final<<<1, 256, 0, stream>>>(multv, eta2, r0a, r1a, r2a, r3a, scal, lss, out);
}

// Round 13
// 269.767 us; speedup vs baseline: 1.2365x; 1.0623x over previous
//
#include <hip/hip_runtime.h>
#include <math.h>

static constexpr int DC  = 4096;   // D_CAT
static constexpr int NM1 = 4095;   // D_CAT - 1
static constexpr int HID = 256;
static constexpr int BB  = 4096;   // batch
static constexpr double LOG2PI_D = 1.8378770664093454835;

typedef __attribute__((ext_vector_type(8))) __bf16 bf16x8;
typedef __attribute__((ext_vector_type(4))) __bf16 bf16x4;
typedef __attribute__((ext_vector_type(2))) __bf16 bf16x2;
typedef __attribute__((ext_vector_type(4))) float  f32x4;

__device__ __forceinline__ void async16(const __bf16* g, __bf16* l) {
    __builtin_amdgcn_global_load_lds(
        (const __attribute__((address_space(1))) void*)g,
        (__attribute__((address_space(3))) void*)l, 16, 0, 0);
}

// ---- pre: decW transpose [0,1024) + Helmert coeffs [1024,1040) + scalars (1040) ----
__global__ __launch_bounds__(256) void k_pre(
    const float* __restrict__ decW, const float* __restrict__ Psi,
    const float* __restrict__ lv, const float* __restrict__ lss,
    __bf16* __restrict__ decWT, float* __restrict__ av, float* __restrict__ bv,
    float* __restrict__ Dv, float* __restrict__ scal)
{
    __shared__ float tp[32][33];
    const int t = threadIdx.x;
    const int blk = blockIdx.x;
    if (blk < 1024) {
        int bx = blk & 7, by = blk >> 3;
        int tx = t & 31, ty = t >> 5;
        int r0 = by * 32, c0 = bx * 32;
        #pragma unroll
        for (int i = 0; i < 4; i++) {
            int r = r0 + ty + i * 8, c = c0 + tx;
            tp[ty + i * 8][tx] = (r < NM1 && c < HID) ? decW[(size_t)r * HID + c] : 0.f;
        }
        __syncthreads();
        #pragma unroll
        for (int i = 0; i < 4; i++) {
            int c = c0 + ty + i * 8, r = r0 + tx;
            decWT[(size_t)c * DC + r] = (__bf16)tp[tx][ty + i * 8];
        }
    } else if (blk < 1040) {
        int r = (blk - 1024) * 256 + t;
        if (r < NM1) {
            av[r] = Psi[(size_t)r * DC];
            bv[r] = -Psi[(size_t)r * DC + r + 1];
        } else { av[r] = 0.f; bv[r] = 0.f; }
    } else {
        float v = lv[t];
        Dv[t] = expf(v);
        for (int o = 32; o > 0; o >>= 1) v += __shfl_down(v, o);
        __shared__ float red[4];
        if ((t & 63) == 0) red[t >> 6] = v;
        __syncthreads();
        if (t == 0) {
            scal[0] = expf(lss[0]);
            scal[1] = red[0] + red[1] + red[2] + red[3];
        }
    }
}

// ---- mega: WtW gemm [0,64) + encscan [64,64+HID) + rows [64+HID, 64+HID+BB) ----
// Round-6 exact version (best measured: 71.5 us, VGPR 68, no spills).
__global__ __launch_bounds__(256) void k_mega(
    const float* __restrict__ x, const float* __restrict__ eta,
    const float* __restrict__ encW, const __bf16* __restrict__ decWT,
    const float* __restrict__ av, const float* __restrict__ bv,
    float* __restrict__ multv, float* __restrict__ eta2,
    __bf16* __restrict__ clrB, __bf16* __restrict__ etaB,
    __bf16* __restrict__ encPsiB, float* __restrict__ WtW)
{
    __shared__ float smemf[2392];
    const int t = threadIdx.x;
    const int blk = blockIdx.x;
    const int lane = t & 63, w = t >> 6;

    if (blk >= 64 + HID) {
        __bf16* es    = (__bf16*)smemf;          // [4096] bf16 = 2048 floats
        float* red    = smemf + 2048;            // [16]
        float* wsumE  = smemf + 2064;            // [4]
        float* wsumX  = smemf + 2068;            // [4]
        float* firstX = smemf + 2072;            // [256]
        float* lutL   = smemf + 2328;            // [32]
        float* lutG   = smemf + 2360;            // [32]
        const int b = blk - (64 + HID);
        const int j0 = t * 16;

        const float4* xrow = (const float4*)(x + (size_t)b * DC + j0);
        float4 xq[4];
        #pragma unroll
        for (int i = 0; i < 4; i++) xq[i] = xrow[i];

        const float* erow = eta + (size_t)b * NM1;
        float ee[16];
        #pragma unroll
        for (int i = 0; i < 16; i++) { int j = i * 256 + t; ee[i] = (j < NM1) ? erow[j] : 0.f; }

        float avc[16], bvc[16];
        #pragma unroll
        for (int i = 0; i < 16; i += 4) {
            float4 a4 = *(const float4*)(av + j0 + i);
            avc[i] = a4.x; avc[i + 1] = a4.y; avc[i + 2] = a4.z; avc[i + 3] = a4.w;
            float4 b4 = *(const float4*)(bv + j0 + i);
            bvc[i] = b4.x; bvc[i + 1] = b4.y; bvc[i + 2] = b4.z; bvc[i + 3] = b4.w;
        }

        if (t < 32) { float f = (float)t + 1.f; lutL[t] = logf(f); lutG[t] = lgammaf(f); }
        __syncthreads();   // B0

        float xv[16], lvv[16];
        #pragma unroll
        for (int i = 0; i < 4; i++) {
            xv[i * 4 + 0] = xq[i].x; xv[i * 4 + 1] = xq[i].y;
            xv[i * 4 + 2] = xq[i].z; xv[i * 4 + 3] = xq[i].w;
        }
        float s = 0.f, slg = 0.f, slp = 0.f;
        #pragma unroll
        for (int i = 0; i < 16; i++) {
            float vf = xv[i];
            int iv = (int)vf;
            float l, g;
            if (vf == (float)iv && iv >= 0 && iv < 32) { l = lutL[iv]; g = lutG[iv]; }
            else { l = logf(vf + 1.f); g = lgammaf(vf + 1.f); }
            lvv[i] = l;
            s += vf; slg += g; slp += l;
        }
        float e2 = 0.f;
        #pragma unroll
        for (int i = 0; i < 16; i++) {
            float e = ee[i];
            e2 += e * e;
            es[i * 256 + t] = (__bf16)e;
        }
        firstX[t] = xv[0];
        for (int o = 32; o > 0; o >>= 1) {
            s += __shfl_down(s, o); slg += __shfl_down(slg, o);
            slp += __shfl_down(slp, o); e2 += __shfl_down(e2, o);
        }
        if (lane == 0) { red[w] = s; red[4 + w] = slg; red[8 + w] = slp; red[12 + w] = e2; }
        __syncthreads();   // B1

        const float ntotv  = red[0] + red[1] + red[2] + red[3];
        const float sumlgv = red[4] + red[5] + red[6] + red[7];
        const float m = (red[8] + red[9] + red[10] + red[11]) * (1.f / DC);

        bf16x8 e0 = *(const bf16x8*)(es + j0);
        bf16x8 e1 = *(const bf16x8*)(es + j0 + 8);
        *(bf16x8*)(etaB + (size_t)b * DC + j0)     = e0;
        *(bf16x8*)(etaB + (size_t)b * DC + j0 + 8) = e1;
        float ev[16];
        #pragma unroll
        for (int i = 0; i < 8; i++) { ev[i] = (float)e0[i]; ev[i + 8] = (float)e1[i]; }

        bf16x8 c0, c1;
        #pragma unroll
        for (int i = 0; i < 8; i++) {
            c0[i] = (__bf16)(lvv[i] - m);
            c1[i] = (__bf16)(lvv[i + 8] - m);
        }
        *(bf16x8*)(clrB + (size_t)b * DC + j0)     = c0;
        *(bf16x8*)(clrB + (size_t)b * DC + j0 + 8) = c1;

        float localE = 0.f, localX = 0.f;
        #pragma unroll
        for (int i = 0; i < 16; i++) { localE += ev[i] * avc[i]; localX += xv[i]; }
        float incE = localE, incX = localX;
        #pragma unroll
        for (int o = 1; o < 64; o <<= 1) {
            float vE = __shfl_up(incE, o), vX = __shfl_up(incX, o);
            if (lane >= o) { incE += vE; incX += vX; }
        }
        if (lane == 63) { wsumE[w] = incE; wsumX[w] = incX; }
        float eprev = (t > 0) ? (float)es[j0 - 1] : 0.f;
        float bprev = (t > 0) ? bv[j0 - 1] : 0.f;
        float xnl   = (t < 255) ? firstX[t + 1] : 0.f;
        __syncthreads();   // B2

        float woffE = 0.f, woffX = 0.f;
        for (int i = 0; i < w; i++) { woffE += wsumE[i]; woffX += wsumX[i]; }
        const float U = wsumE[0] + wsumE[1] + wsumE[2] + wsumE[3];
        float runE = woffE + incE - localE;
        float Xrun = woffX + incX - localX;

        float se = 0.f, sx = 0.f;
        #pragma unroll
        for (int i = 0; i < 16; i++) {
            float Tj = U - runE;
            runE += ev[i] * avc[i];
            float pw = (i == 0) ? eprev * bprev : ev[i - 1] * bvc[i - 1];
            float l = Tj - pw;
            se += expf(l);
            Xrun += xv[i];
            float xn = (i < 15) ? xv[i + 1] : xnl;
            sx += ev[i] * (avc[i] * Xrun - bvc[i] * xn);
        }
        for (int o = 32; o > 0; o >>= 1) {
            se += __shfl_down(se, o); sx += __shfl_down(sx, o);
        }
        if (lane == 0) { red[0 + w] = se; red[4 + w] = sx; }
        __syncthreads();   // B3
        if (t == 0) {
            float S1t = red[0] + red[1] + red[2] + red[3];
            float S2t = red[4] + red[5] + red[6] + red[7];
            float e2t = red[12] + red[13] + red[14] + red[15];
            double mult = (double)lgammaf(ntotv + 1.f) - (double)sumlgv
                        + (double)S2t - (double)ntotv * (double)logf(S1t);
            multv[b] = (float)mult;
            eta2[b]  = e2t;
        }
    } else if (blk >= 64) {
        // ---------------- encscan ----------------
        __bf16* es   = (__bf16*)smemf;
        float* wsumE = smemf + 2048;
        const int h = blk - 64;
        const float* erow = encW + (size_t)h * NM1;
        float ee[16];
        #pragma unroll
        for (int i = 0; i < 16; i++) { int j = i * 256 + t; ee[i] = (j < NM1) ? erow[j] : 0.f; }
        const int j0 = t * 16;
        float avc[16], bvc[16];
        #pragma unroll
        for (int i = 0; i < 16; i += 4) {
            float4 a4 = *(const float4*)(av + j0 + i);
            avc[i] = a4.x; avc[i + 1] = a4.y; avc[i + 2] = a4.z; avc[i + 3] = a4.w;
            float4 b4 = *(const float4*)(bv + j0 + i);
            bvc[i] = b4.x; bvc[i + 1] = b4.y; bvc[i + 2] = b4.z; bvc[i + 3] = b4.w;
        }
        #pragma unroll
        for (int i = 0; i < 16; i++) es[i * 256 + t] = (__bf16)ee[i];
        __syncthreads();
        float ev[16];
        {
            bf16x8 ea = *(const bf16x8*)(es + j0), eb8 = *(const bf16x8*)(es + j0 + 8);
            #pragma unroll
            for (int i = 0; i < 8; i++) { ev[i] = (float)ea[i]; ev[i + 8] = (float)eb8[i]; }
        }
        float localE = 0.f;
        #pragma unroll
        for (int i = 0; i < 16; i++) localE += ev[i] * avc[i];
        float incE = localE;
        #pragma unroll
        for (int o = 1; o < 64; o <<= 1) { float vE = __shfl_up(incE, o); if (lane >= o) incE += vE; }
        if (lane == 63) wsumE[w] = incE;
        float eprev = (t > 0) ? (float)es[j0 - 1] : 0.f;
        float bprev = (t > 0) ? bv[j0 - 1] : 0.f;
        __syncthreads();
        float woffE = 0.f;
        for (int i = 0; i < w; i++) woffE += wsumE[i];
        const float U = wsumE[0] + wsumE[1] + wsumE[2] + wsumE[3];
        float runE = woffE + incE - localE;
        bf16x8 o0, o1;
        #pragma unroll
        for (int i = 0; i < 16; i++) {
            float Tj = U - runE;
            runE += ev[i] * avc[i];
            float pw = (i == 0) ? eprev * bprev : ev[i - 1] * bvc[i - 1];
            float l = Tj - pw;
            if (i < 8) o0[i] = (__bf16)l; else o1[i - 8] = (__bf16)l;
        }
        *(bf16x8*)(encPsiB + (size_t)h * DC + j0)     = o0;
        *(bf16x8*)(encPsiB + (size_t)h * DC + j0 + 8) = o1;
    } else {
        // ---------------- WtW = decWT @ decWT^T, 64x64 tiles x 4 K-slices ----------------
        __bf16* As = (__bf16*)smemf;            // 64x32 = 4 KB
        __bf16* Bs = (__bf16*)(smemf + 1024);   // 64x32 = 4 KB
        const int w2 = blk;                     // 0..63
        const int mn = w2 & 15, sl = w2 >> 4;
        const int m0 = (mn >> 2) * 64, n0 = (mn & 3) * 64, kb = sl * 1024;
        const int ln = lane & 15, q = lane >> 4;
        const int wm = w >> 1, wn = w & 1;
        f32x4 acc[2][2] = {};
        for (int k0 = kb; k0 < kb + 1024; k0 += 32) {
            async16(decWT + (size_t)(m0 + (t >> 2)) * DC + k0 + (t & 3) * 8, As + t * 8);
            async16(decWT + (size_t)(n0 + (t >> 2)) * DC + k0 + (t & 3) * 8, Bs + t * 8);
            __syncthreads();
            bf16x8 af[2], bfr[2];
            #pragma unroll
            for (int i = 0; i < 2; i++) {
                af[i]  = *(const bf16x8*)(As + (wm * 32 + i * 16 + ln) * 32 + q * 8);
                bfr[i] = *(const bf16x8*)(Bs + (wn * 32 + i * 16 + ln) * 32 + q * 8);
            }
            #pragma unroll
            for (int mi = 0; mi < 2; mi++)
                #pragma unroll
                for (int ni = 0; ni < 2; ni++)
                    acc[mi][ni] = __builtin_amdgcn_mfma_f32_16x16x32_bf16(af[mi], bfr[ni], acc[mi][ni], 0, 0, 0);
            __syncthreads();
        }
        #pragma unroll
        for (int mi = 0; mi < 2; mi++)
            #pragma unroll
            for (int rr = 0; rr < 4; rr++) {
                int m = m0 + wm * 32 + mi * 16 + q * 4 + rr;
                #pragma unroll
                for (int ni = 0; ni < 2; ni++)
                    atomicAdd(&WtW[(size_t)m * HID + n0 + wn * 32 + ni * 16 + ln], acc[mi][ni][rr]);
            }
    }
}

// ---- combo2: cap [0,16) + z_mean/etaW GEMMs [16,1040) ----
// N-split 128 + double-buffered 2-phase pipeline: LDS 48 KB -> 3 blocks/CU
// with dbuf. Counted vmcnt(6); raw barriers; lgkmcnt(0)+sched_barrier(0)
// before buffer swap (rule #18). Plain-store split-K partials.
__global__ __launch_bounds__(256) void k_combo2(
    const __bf16* __restrict__ clrB, const __bf16* __restrict__ etaB,
    const __bf16* __restrict__ encPsiB, const __bf16* __restrict__ decWT,
    float* __restrict__ part,
    const float* __restrict__ WtW, const float* __restrict__ Dv,
    const float* __restrict__ scal, __bf16* __restrict__ WtWB,
    __bf16* __restrict__ MinvB, float* __restrict__ scal_out)
{
    __shared__ __bf16 AsB[2][64 * 64];    // 2 x 8 KB
    __shared__ __bf16 BsB[2][128 * 64];   // 2 x 16 KB
    const int tid = threadIdx.x;
    const int w = tid >> 6, lane = tid & 63;
    const int ln = lane & 15, q = lane >> 4;
    const int wm = w >> 1, wn = w & 1;
    const int bid = blockIdx.x;

    if (bid >= 16) {
        const int idx = bid - 16;            // 0..1023
        const int g = idx >> 9;              // 0: z_mean, 1: etaW
        const int r = idx & 511;
        const int sl = r >> 7;               // K-slice 0..3
        const int mt = (r & 127) >> 1;       // 0..63
        const int nt = r & 1;                // 0..1
        const __bf16* A  = g ? etaB  : clrB;
        const __bf16* Bt = g ? decWT : encPsiB;
        float* C = part + ((size_t)(g * 4 + sl) << 20);
        const int m0 = mt * 64, n0 = nt * 128, kb = sl * 1024;

        auto stage = [&](int buf, int k0) {
            #pragma unroll
            for (int j = 0; j < 2; j++) {
                int c = j * 256 + tid;
                int row = c >> 3, ch = c & 7;
                async16(A + (size_t)(m0 + row) * DC + k0 + (ch ^ (row & 7)) * 8,
                        &AsB[buf][c * 8]);
            }
            #pragma unroll
            for (int j = 0; j < 4; j++) {
                int c = j * 256 + tid;
                int row = c >> 3, ch = c & 7;
                async16(Bt + (size_t)(n0 + row) * DC + k0 + (ch ^ (row & 7)) * 8,
                        &BsB[buf][c * 8]);
            }
        };

        f32x4 acc[2][4] = {};
        stage(0, kb);
        int cur = 0;
        for (int t = 0; t < 16; t++) {
            if (t < 15) {
                stage(cur ^ 1, kb + (t + 1) * 64);
                asm volatile("s_waitcnt vmcnt(6)" ::: "memory");
            } else {
                asm volatile("s_waitcnt vmcnt(0)" ::: "memory");
            }
            __builtin_amdgcn_s_barrier();
            const __bf16* As = AsB[cur];
            const __bf16* Bs = BsB[cur];
            #pragma unroll
            for (int jj = 0; jj < 2; jj++) {
                bf16x8 af[2], bfr[4];
                #pragma unroll
                for (int i = 0; i < 2; i++) {
                    int arow = wm * 32 + i * 16 + ln;
                    af[i]  = *(const bf16x8*)(As + arow * 64 + ((jj * 4 + q) ^ (arow & 7)) * 8);
                }
                #pragma unroll
                for (int i = 0; i < 4; i++) {
                    int brow = wn * 64 + i * 16 + ln;
                    bfr[i] = *(const bf16x8*)(Bs + brow * 64 + ((jj * 4 + q) ^ (brow & 7)) * 8);
                }
                #pragma unroll
                for (int mi = 0; mi < 2; mi++)
                    #pragma unroll
                    for (int ni = 0; ni < 4; ni++)
                        acc[mi][ni] = __builtin_amdgcn_mfma_f32_16x16x32_bf16(af[mi], bfr[ni], acc[mi][ni], 0, 0, 0);
            }
            asm volatile("s_waitcnt lgkmcnt(0)" ::: "memory");
            __builtin_amdgcn_sched_barrier(0);
            __builtin_amdgcn_s_barrier();
            cur ^= 1;
        }
        #pragma unroll
        for (int mi = 0; mi < 2; mi++)
            #pragma unroll
            for (int rr = 0; rr < 4; rr++) {
                int m = m0 + wm * 32 + mi * 16 + q * 4 + rr;
                #pragma unroll
                for (int ni = 0; ni < 4; ni++) {
                    int n = n0 + wn * 64 + ni * 16 + ln;
                    C[(size_t)m * HID + n] = acc[mi][ni][rr];
                }
            }
    } else {
        // ---- cap: B2 = B@B (64x64 tile); Minv = (I - B + B2)*diag(Dv); traces ----
        __shared__ float dvs[HID];
        __shared__ float redc[8];
        __bf16* As = AsB[0];
        __bf16* Bs = BsB[0];
        const int w2 = bid;
        const int m0 = (w2 >> 2) * 64, n0 = (w2 & 3) * 64;
        dvs[tid] = Dv[tid];
        __syncthreads();
        const float rv = 1.f / scal[0];
        f32x4 acc[2][2] = {};
        for (int k0 = 0; k0 < HID; k0 += 32) {
            {
                int row = tid >> 2, kc = tid & 3;
                const float* srcA = WtW + (size_t)(m0 + row) * HID + k0 + kc * 8;
                const float* srcB = WtW + (size_t)(n0 + row) * HID + k0 + kc * 8;
                float sA = dvs[m0 + row] * rv;
                bf16x8 a8, b8;
                #pragma unroll
                for (int u = 0; u < 8; u++) {
                    a8[u] = (__bf16)(srcA[u] * sA);
                    b8[u] = (__bf16)(srcB[u] * dvs[k0 + kc * 8 + u] * rv);
                }
                *(bf16x8*)(As + tid * 8) = a8;
                *(bf16x8*)(Bs + tid * 8) = b8;
            }
            __syncthreads();
            bf16x8 af[2], bfr[2];
            #pragma unroll
            for (int i = 0; i < 2; i++) {
                af[i]  = *(const bf16x8*)(As + (wm * 32 + i * 16 + ln) * 32 + q * 8);
                bfr[i] = *(const bf16x8*)(Bs + (wn * 32 + i * 16 + ln) * 32 + q * 8);
            }
            #pragma unroll
            for (int mi = 0; mi < 2; mi++)
                #pragma unroll
                for (int ni = 0; ni < 2; ni++)
                    acc[mi][ni] = __builtin_amdgcn_mfma_f32_16x16x32_bf16(af[mi], bfr[ni], acc[mi][ni], 0, 0, 0);
            __syncthreads();
        }
        float t1p = 0.f, t2p = 0.f;
        #pragma unroll
        for (int mi = 0; mi < 2; mi++)
            #pragma unroll
            for (int rr = 0; rr < 4; rr++) {
                int m = m0 + wm * 32 + mi * 16 + q * 4 + rr;
                #pragma unroll
                for (int ni = 0; ni < 2; ni++) {
                    int n = n0 + wn * 32 + ni * 16 + ln;
                    float wmn = WtW[(size_t)m * HID + n];
                    float Bmn = dvs[m] * wmn * rv;
                    float Bnm = dvs[n] * wmn * rv;
                    float mv = (((m == n) ? 1.f : 0.f) - Bmn + acc[mi][ni][rr]) * dvs[n];
                    MinvB[(size_t)m * HID + n] = (__bf16)mv;
                    WtWB[(size_t)m * HID + n] = (__bf16)wmn;
                    t2p += Bmn * Bnm;
                    if (m == n) t1p += Bmn;
                }
            }
        for (int o = 32; o > 0; o >>= 1) { t1p += __shfl_down(t1p, o); t2p += __shfl_down(t2p, o); }
        if (lane == 0) { redc[w] = t1p; redc[4 + w] = t2p; }
        __syncthreads();
        if (tid == 0) {
            atomicAdd(&scal_out[2], redc[0] + redc[1] + redc[2] + redc[3]);
            atomicAdd(&scal_out[3], redc[4] + redc[5] + redc[6] + redc[7]);
        }
    }
}

// ---- fused quad: Zw = z@WtW, dW in LDS, T = dW@Minv, row dots; 16-row tiles ----
__global__ __launch_bounds__(256) void mfma_quad(
    const float* __restrict__ part,
    const __bf16* __restrict__ WtWB, const __bf16* __restrict__ MinvB,
    float* __restrict__ r0a, float* __restrict__ r1a, float* __restrict__ r2a,
    float* __restrict__ r3a)
{
    __shared__ __bf16 As[16 * 32];
    __shared__ __bf16 Bs[256 * 32];
    __shared__ __bf16 dWs[16 * 264];
    const int tid = threadIdx.x;
    const int w = tid >> 6, lane = tid & 63;
    const int ln = lane & 15, q = lane >> 4;
    const int m0 = blockIdx.x * 16;
    const float* zp = part;
    const float* ep = part + ((size_t)4 << 20);
    const size_t SL = (size_t)1 << 20;

    f32x4 acc[4] = {};
    for (int k0 = 0; k0 < HID; k0 += 32) {
        {
            int row = tid >> 4, kc = tid & 15;
            size_t off = (size_t)(m0 + row) * HID + k0 + kc * 2;
            float2 v0 = *(const float2*)(zp + off);
            float2 v1 = *(const float2*)(zp + SL + off);
            float2 v2 = *(const float2*)(zp + 2 * SL + off);
            float2 v3 = *(const float2*)(zp + 3 * SL + off);
            float vx = v0.x + v1.x + v2.x + v3.x;
            float vy = v0.y + v1.y + v2.y + v3.y;
            bf16x2 b2 = {(__bf16)vx, (__bf16)vy};
            int ch = kc >> 2, wi = kc & 3;
            *(bf16x2*)(As + row * 32 + ((ch ^ ((row >> 1) & 3)) * 8) + wi * 2) = b2;
        }
        #pragma unroll
        for (int j = 0; j < 4; j++) {
            int c = j * 256 + tid;
            int row = c >> 2, ch = c & 3;
            async16(WtWB + (size_t)row * HID + k0 + (ch ^ ((row >> 1) & 3)) * 8, Bs + c * 8);
        }
        __syncthreads();
        bf16x8 af = *(const bf16x8*)(As + ln * 32 + ((q ^ ((ln >> 1) & 3)) * 8));
        #pragma unroll
        for (int ni = 0; ni < 4; ni++) {
            int brow = w * 64 + ni * 16 + ln;
            bf16x8 bfr = *(const bf16x8*)(Bs + brow * 32 + ((q ^ ((ln >> 1) & 3)) * 8));
            acc[ni] = __builtin_amdgcn_mfma_f32_16x16x32_bf16(af, bfr, acc[ni], 0, 0, 0);
        }
        __syncthreads();
    }
    #pragma unroll
    for (int rr = 0; rr < 4; rr++) {
        int lm = q * 4 + rr;
        int m = m0 + lm;
        float s0 = 0.f, s1 = 0.f, s3 = 0.f;
        #pragma unroll
        for (int ni = 0; ni < 4; ni++) {
            int n = w * 64 + ni * 16 + ln;
            size_t o2 = (size_t)m * HID + n;
            float zv = zp[o2] + zp[SL + o2] + zp[2 * SL + o2] + zp[3 * SL + o2];
            float ew = ep[o2] + ep[SL + o2] + ep[2 * SL + o2] + ep[3 * SL + o2];
            float dv = ew - acc[ni][rr];
            dWs[lm * 264 + n] = (__bf16)dv;
            s0 += ew * zv; s1 += dv * zv; s3 += zv * zv;
        }
        #pragma unroll
        for (int o = 1; o < 16; o <<= 1) {
            s0 += __shfl_xor(s0, o); s1 += __shfl_xor(s1, o); s3 += __shfl_xor(s3, o);
        }
        if (ln == 0) {
            atomicAdd(&r0a[m], s0); atomicAdd(&r1a[m], s1); atomicAdd(&r3a[m], s3);
        }
    }

    f32x4 acc2[4] = {};
    for (int k0 = 0; k0 < HID; k0 += 32) {
        #pragma unroll
        for (int j = 0; j < 4; j++) {
            int c = j * 256 + tid;
            int row = c >> 2, ch = c & 3;
            async16(MinvB + (size_t)row * HID + k0 + (ch ^ ((row >> 1) & 3)) * 8, Bs + c * 8);
        }
        __syncthreads();
        bf16x8 af = *(const bf16x8*)(dWs + ln * 264 + k0 + q * 8);
        #pragma unroll
        for (int ni = 0; ni < 4; ni++) {
            int brow = w * 64 + ni * 16 + ln;
            bf16x8 bfr = *(const bf16x8*)(Bs + brow * 32 + ((q ^ ((ln >> 1) & 3)) * 8));
            acc2[ni] = __builtin_amdgcn_mfma_f32_16x16x32_bf16(af, bfr, acc2[ni], 0, 0, 0);
        }
        __syncthreads();
    }
    #pragma unroll
    for (int rr = 0; rr < 4; rr++) {
        int lm = q * 4 + rr;
        int m = m0 + lm;
        float s2 = 0.f;
        #pragma unroll
        for (int ni = 0; ni < 4; ni++) {
            int n = w * 64 + ni * 16 + ln;
            s2 += (float)dWs[lm * 264 + n] * acc2[ni][rr];
        }
        #pragma unroll
        for (int o = 1; o < 16; o <<= 1) s2 += __shfl_xor(s2, o);
        if (ln == 0) atomicAdd(&r2a[m], s2);
    }
}

// ---- final assembly ----
__global__ void k_final(const float* __restrict__ multv, const float* __restrict__ eta2,
                        const float* __restrict__ r0a, const float* __restrict__ r1a,
                        const float* __restrict__ r2a, const float* __restrict__ r3a,
                        const float* __restrict__ scal, const float* __restrict__ lss,
                        float* __restrict__ out) {
    int t = threadIdx.x;
    float var = scal[0];
    float rv = 1.f / var;
    double am = 0.0, aq = 0.0, az = 0.0;
    for (int b = t; b < BB; b += 256) {
        am += (double)multv[b];
        aq += (double)((eta2[b] - r0a[b] - r1a[b]) * rv - r2a[b] * rv * rv);
        az += (double)r3a[b];
    }
    for (int o = 32; o > 0; o >>= 1) {
        am += __shfl_down(am, o); aq += __shfl_down(aq, o); az += __shfl_down(az, o);
    }
    __shared__ double red[3][4];
    if ((t & 63) == 0) { int w = t >> 6; red[0][w] = am; red[1][w] = aq; red[2][w] = az; }
    __syncthreads();
    if (t == 0) {
        double mm = (red[0][0] + red[0][1] + red[0][2] + red[0][3]) / (double)BB;
        double mq = (red[1][0] + red[1][1] + red[1][2] + red[1][3]) / (double)BB;
        double mz = (red[2][0] + red[2][1] + red[2][2] + red[2][3]) / ((double)BB * (double)HID);
        double t1 = scal[2], t2 = scal[3];
        double logdetIB = t1 - t2 * 0.5;
        double sumlv = (double)scal[1];
        double logdetM = -sumlv + logdetIB;
        double logdet_sigma = (double)NM1 * (double)lss[0] + sumlv + logdetM;
        double logit_loss = -0.5 * ((double)NM1 * LOG2PI_D + logdet_sigma + mq);
        double prior_loss = -0.5 * mz - 0.5 * LOG2PI_D;
        out[0] = (float)(-(mm + logit_loss + prior_loss));
    }
}

// ---------------- launcher ----------------

extern "C" void kernel_launch(void* const* d_in, const int* in_sizes, int n_in,
                              void* d_out, int out_size, void* d_ws, size_t ws_size,
                              hipStream_t stream) {
    (void)in_sizes; (void)n_in; (void)out_size; (void)ws_size;
    const float* x    = (const float*)d_in[0];
    const float* Psi  = (const float*)d_in[1];
    const float* encW = (const float*)d_in[2];
    const float* decW = (const float*)d_in[3];
    const float* lv   = (const float*)d_in[4];
    const float* lss  = (const float*)d_in[5];
    const float* eta  = (const float*)d_in[6];
    float* out = (float*)d_out;

    float* wp = (float*)d_ws;
    // --- split-K partials: z slices [0,4), etaW slices [4,8), 1M floats each ---
    float* part   = wp;                      // 8M floats = 32 MB (fully overwritten)
    // --- contiguous memset region (atomic targets) ---
    float* WtW    = part + ((size_t)8 << 20); // 64K
    float* r0a    = WtW    + 65536;          // 4K each
    float* r1a    = r0a    + 4096;
    float* r2a    = r1a    + 4096;
    float* r3a    = r2a    + 4096;
    float* scal   = r3a    + 4096;           // 16
    // --- rest ---
    float* av     = scal   + 16;
    float* bv     = av     + 4096;
    float* multv  = bv     + 4096;
    float* eta2   = multv  + 4096;
    float* Dv     = eta2   + 4096;           // 256
    __bf16* clrB    = (__bf16*)(Dv + 256);
    __bf16* etaB    = clrB    + (1 << 24);
    __bf16* encPsiB = etaB    + (1 << 24);   // 1M
    __bf16* decWT   = encPsiB + (1 << 20);   // 1M
    __bf16* WtWB    = decWT   + (1 << 20);   // 64K each
    __bf16* MinvB   = WtWB    + 65536;

    hipMemsetAsync(WtW, 0, (size_t)(65536 + 4 * 4096 + 16) * sizeof(float), stream);

    k_pre<<<1041, 256, 0, stream>>>(decW, Psi, lv, lss, decWT, av, bv, Dv, scal);

    k_mega<<<64 + HID + BB, 256, 0, stream>>>(x, eta, encW, decWT, av, bv,
                                              multv, eta2, clrB, etaB, encPsiB, WtW);

    k_combo2<<<1040, 256, 0, stream>>>(clrB, etaB, encPsiB, decWT, part,
                                       WtW, Dv, scal, WtWB, MinvB, scal);

    mfma_quad<<<256, 256, 0, stream>>>(part, WtWB, MinvB, r0a, r1a, r2a, r3a);

    k_final<<<1, 256, 0, stream>>>(multv, eta2, r0a, r1a, r2a, r3a, scal, lss, out);
}